// Round 5
// baseline (338.242 us; speedup 1.0000x reference)
//
#include <hip/hip_runtime.h>
#include <stdint.h>

#define NN 50000
#define NE 800000
#define CAP 64   // slot capacity per node; P(Binom(800K,1/50K) >= 64) ~ 1e-30
// layer1: in=128 hid=256; layer2: in=256 out=128
// Layer-2 restructured: out = mean_agg(h @ W2_l^T) + (h @ W2_r^T + b2)
// CSR replaced by fixed-capacity slot table: slots[node][CAP], deg = cursor[node].

typedef __bf16 bf16x8 __attribute__((ext_vector_type(8)));
typedef float  f32x4  __attribute__((ext_vector_type(4)));

__device__ __forceinline__ unsigned short f2bf(float f) {
    unsigned int u = __float_as_uint(f);
    unsigned int r = (u + 0x7fffu + ((u >> 16) & 1u)) >> 16;   // RNE
    return (unsigned short)r;
}
__device__ __forceinline__ float bf_lo(unsigned int v) { return __uint_as_float(v << 16); }
__device__ __forceinline__ float bf_hi(unsigned int v) { return __uint_as_float(v & 0xffff0000u); }

// ---------------- prep: zero cursor + detect edge dtype ----------------
// blocks 0..195: zero cursor; block 196: detect int64-vs-int32 storage.
__global__ __launch_bounds__(256) void prep_kernel(const int* __restrict__ edges,
                                                   int* __restrict__ cursor,
                                                   int* __restrict__ flag) {
    int b = blockIdx.x;
    if (b < 196) {
        int g = b * 256 + threadIdx.x;
        if (g < NN) cursor[g] = 0;
    } else {
        __shared__ int nz;
        if (threadIdx.x == 0) nz = 0;
        __syncthreads();
        for (int i = threadIdx.x; i < 512; i += 256)
            if (edges[2 * i + 1] != 0) atomicOr(&nz, 1);
        __syncthreads();
        if (threadIdx.x == 0) *flag = nz ? 0 : 1;  // 1 => int64 storage
    }
}

// ---------------- fill_mega: slot fill + cast_x + packB in one dispatch ----------------
// blocks [0,391):      fill slots (8 edges/thread, pipelined atomic chains)
// blocks [391,903):    pack B1/B2 (131072 elems)
// blocks [903,7153):   cast x f32->bf16 (float4 per thread)
#define FILL_NB 391
#define PACK_NB 512
#define CAST_NB 6250
__global__ __launch_bounds__(256) void fill_mega_kernel(
    const int* __restrict__ edges, const int* __restrict__ flag,
    int* __restrict__ cursor, int* __restrict__ slots,
    const float* __restrict__ x,
    const float* __restrict__ W1l, const float* __restrict__ W1r,
    const float* __restrict__ W2l, const float* __restrict__ W2r,
    unsigned short* __restrict__ x_bf,
    unsigned short* __restrict__ B1, unsigned short* __restrict__ B2) {
    int b = blockIdx.x;
    if (b < FILL_NB) {
        int f = *flag;
        int base = (b * 256 + threadIdx.x) * 8;
        const int E = NE;
        if (base + 8 <= E) {
            int s[8], d[8], pos[8];
#pragma unroll
            for (int u = 0; u < 8; ++u) {
                s[u] = edges[(size_t)(base + u) << f];
                d[u] = edges[(size_t)(E + base + u) << f];
            }
#pragma unroll
            for (int u = 0; u < 8; ++u) pos[u] = atomicAdd(&cursor[d[u]], 1);
#pragma unroll
            for (int u = 0; u < 8; ++u)
                if (pos[u] < CAP) slots[((size_t)d[u] << 6) + pos[u]] = s[u];
        } else {
            for (int e = base; e < E; ++e) {
                int s0 = edges[(size_t)e << f];
                int d0 = edges[(size_t)(E + e) << f];
                int p = atomicAdd(&cursor[d0], 1);
                if (p < CAP) slots[((size_t)d0 << 6) + p] = s0;
            }
        }
    } else if (b < FILL_NB + PACK_NB) {
        int idx = (b - FILL_NB) * 256 + threadIdx.x;   // 0..131071
        if (idx < 65536) {
            int o = idx >> 8, k = idx & 255;
            float v = (k < 128) ? W1l[o * 128 + k] : W1r[o * 128 + (k - 128)];
            B1[idx] = f2bf(v);
        } else {
            int j = idx - 65536;
            int o = j >> 8, k = j & 255;
            float v = (o < 128) ? W2l[o * 256 + k] : W2r[(o - 128) * 256 + k];
            B2[j] = f2bf(v);
        }
    } else {
        int i4 = (b - FILL_NB - PACK_NB) * 256 + threadIdx.x;  // 0..1599999 (=N*128/4)
        float4 v = *(const float4*)(x + (size_t)i4 * 4);
        uint2 p;
        p.x = (unsigned int)f2bf(v.x) | ((unsigned int)f2bf(v.y) << 16);
        p.y = (unsigned int)f2bf(v.z) | ((unsigned int)f2bf(v.w) << 16);
        *(uint2*)(x_bf + (size_t)i4 * 4) = p;
    }
}

// ---------------- gemm1_fused: mean-agg (rows of this block) + MFMA GEMM ----------------
// h[m,n] = relu( sum_k [mean1 || x_bf][m,k] * B1[n,k] + b1[n] ), output bf16 [N,256].
// Phase 1: wave w computes mean rows w*16..w*16+15 into meanbuf (full wave per row).
// Phase 2: 4 K-slices of 64; slices 0,1 read A from meanbuf, slices 2,3 stage x_bf.
#define LDK 72
#define LDM 136
__global__ __launch_bounds__(256) void gemm1_fused_kernel(
    const unsigned short* __restrict__ X, const int* __restrict__ cursor,
    const int* __restrict__ slots, const unsigned short* __restrict__ B,
    const float* __restrict__ bias, unsigned short* __restrict__ outBF, int N) {
    __shared__ unsigned short meanbuf[64 * LDM];  // 17408 B
    __shared__ unsigned short As[64 * LDK];       //  9216 B
    __shared__ unsigned short Bs[256 * LDK];      // 36864 B  (total 63488 B)
    int tid = threadIdx.x;
    int row0 = blockIdx.x * 64;
    int w = tid >> 6, lane = tid & 63;
    int q = lane >> 4, l16 = lane & 15;

    // ---- phase 1: mean aggregation for this block's 64 rows ----
    for (int rr = 0; rr < 16; ++rr) {
        int r = w * 16 + rr;
        int node = row0 + r;
        float ax = 0.f, ay = 0.f;
        if (node < N) {
            int deg = cursor[node];
            int degc = deg < CAP ? deg : CAP;
            const int* sl = slots + ((size_t)node << 6);
            int i = 0;
            for (; i + 8 <= degc; i += 8) {
                unsigned int v[8];
#pragma unroll
                for (int u = 0; u < 8; ++u) {
                    int s = sl[i + u];
                    v[u] = *(const unsigned int*)(X + ((size_t)s << 7) + lane * 2);
                }
#pragma unroll
                for (int u = 0; u < 8; ++u) { ax += bf_lo(v[u]); ay += bf_hi(v[u]); }
            }
            for (; i < degc; ++i) {
                int s = sl[i];
                unsigned int v = *(const unsigned int*)(X + ((size_t)s << 7) + lane * 2);
                ax += bf_lo(v); ay += bf_hi(v);
            }
            float inv = 1.0f / (float)(deg > 1 ? deg : 1);
            ax *= inv; ay *= inv;
        }
        unsigned int p = (unsigned int)f2bf(ax) | ((unsigned int)f2bf(ay) << 16);
        *(unsigned int*)&meanbuf[r * LDM + lane * 2] = p;
    }

    f32x4 acc[4][4];
#pragma unroll
    for (int r = 0; r < 4; ++r)
#pragma unroll
        for (int c = 0; c < 4; ++c) acc[r][c] = (f32x4){0.f, 0.f, 0.f, 0.f};

    // ---- phase 2: K loop (K=256: [0,128) = meanbuf, [128,256) = x_bf) ----
    for (int ks = 0; ks < 4; ++ks) {
        int kbase = ks * 64;
        if (ks) __syncthreads();
        if (ks >= 2) {
            // stage A slice from x_bf (k-kbase in [0,64), x col = kbase-128+..)
#pragma unroll
            for (int i = 0; i < 2; ++i) {
                int lin = tid + 256 * i;
                int r = lin >> 3, g = lin & 7;
                uint4 av = make_uint4(0, 0, 0, 0);
                int grow = row0 + r;
                if (grow < N)
                    av = *(const uint4*)(X + ((size_t)grow << 7) + (kbase - 128) + g * 8);
                *(uint4*)&As[r * LDK + g * 8] = av;
            }
        }
        // stage B slice
#pragma unroll
        for (int i = 0; i < 8; ++i) {
            int lin = tid + 256 * i;
            int n = lin >> 3, g = lin & 7;
            *(uint4*)&Bs[n * LDK + g * 8] = *(const uint4*)(B + ((size_t)n << 8) + kbase + g * 8);
        }
        __syncthreads();
#pragma unroll
        for (int k0 = 0; k0 < 64; k0 += 32) {
            bf16x8 bfrag[4], afrag[4];
#pragma unroll
            for (int c = 0; c < 4; ++c)
                bfrag[c] = *(const bf16x8*)&Bs[(w * 64 + c * 16 + l16) * LDK + k0 + q * 8];
#pragma unroll
            for (int r = 0; r < 4; ++r) {
                if (ks < 2)
                    afrag[r] = *(const bf16x8*)&meanbuf[(r * 16 + l16) * LDM + kbase + k0 + q * 8];
                else
                    afrag[r] = *(const bf16x8*)&As[(r * 16 + l16) * LDK + k0 + q * 8];
            }
#pragma unroll
            for (int r = 0; r < 4; ++r)
#pragma unroll
                for (int c = 0; c < 4; ++c)
                    acc[r][c] = __builtin_amdgcn_mfma_f32_16x16x32_bf16(afrag[r], bfrag[c], acc[r][c], 0, 0, 0);
        }
    }

    // epilogue: D col = lane&15, row = q*4 + reg;  relu + bf16 store
#pragma unroll
    for (int c = 0; c < 4; ++c) {
        int colg = w * 64 + c * 16 + l16;
        float bb = bias[colg];
#pragma unroll
        for (int r = 0; r < 4; ++r) {
#pragma unroll
            for (int reg = 0; reg < 4; ++reg) {
                int rowg = row0 + r * 16 + q * 4 + reg;
                if (rowg < N) {
                    float v = fmaxf(acc[r][c][reg] + bb, 0.f);
                    outBF[((size_t)rowg << 8) + colg] = f2bf(v);
                }
            }
        }
    }
}

// ---------------- gemm2: [P||R] = h @ B2^T ; P bf16 (cols<128), R f32 (+b2) ----------------
__global__ __launch_bounds__(256) void gemm2_kernel(
    const unsigned short* __restrict__ A, const unsigned short* __restrict__ B,
    const float* __restrict__ biasF,
    unsigned short* __restrict__ P, float* __restrict__ R, int N) {
    __shared__ unsigned short As[64 * LDK];
    __shared__ unsigned short Bs[256 * LDK];
    int tid = threadIdx.x;
    int row0 = blockIdx.x * 64;
    int w = tid >> 6, lane = tid & 63;
    int q = lane >> 4, l16 = lane & 15;

    f32x4 acc[4][4];
#pragma unroll
    for (int r = 0; r < 4; ++r)
#pragma unroll
        for (int c = 0; c < 4; ++c) acc[r][c] = (f32x4){0.f, 0.f, 0.f, 0.f};

    for (int ks = 0; ks < 4; ++ks) {
        int kbase = ks * 64;
        if (ks) __syncthreads();
#pragma unroll
        for (int i = 0; i < 2; ++i) {
            int lin = tid + 256 * i;
            int r = lin >> 3, g = lin & 7;
            uint4 av = make_uint4(0, 0, 0, 0);
            int grow = row0 + r;
            if (grow < N) av = *(const uint4*)(A + ((size_t)grow << 8) + kbase + g * 8);
            *(uint4*)&As[r * LDK + g * 8] = av;
        }
#pragma unroll
        for (int i = 0; i < 8; ++i) {
            int lin = tid + 256 * i;
            int n = lin >> 3, g = lin & 7;
            *(uint4*)&Bs[n * LDK + g * 8] = *(const uint4*)(B + ((size_t)n << 8) + kbase + g * 8);
        }
        __syncthreads();
#pragma unroll
        for (int k0 = 0; k0 < 64; k0 += 32) {
            bf16x8 bfrag[4], afrag[4];
#pragma unroll
            for (int c = 0; c < 4; ++c)
                bfrag[c] = *(const bf16x8*)&Bs[(w * 64 + c * 16 + l16) * LDK + k0 + q * 8];
#pragma unroll
            for (int r = 0; r < 4; ++r)
                afrag[r] = *(const bf16x8*)&As[(r * 16 + l16) * LDK + k0 + q * 8];
#pragma unroll
            for (int r = 0; r < 4; ++r)
#pragma unroll
                for (int c = 0; c < 4; ++c)
                    acc[r][c] = __builtin_amdgcn_mfma_f32_16x16x32_bf16(afrag[r], bfrag[c], acc[r][c], 0, 0, 0);
        }
    }

#pragma unroll
    for (int c = 0; c < 4; ++c) {
        int colg = w * 64 + c * 16 + l16;
        bool isBF = (colg < 128);
        float bb = isBF ? 0.f : biasF[colg - 128];
#pragma unroll
        for (int r = 0; r < 4; ++r) {
#pragma unroll
            for (int reg = 0; reg < 4; ++reg) {
                int rowg = row0 + r * 16 + q * 4 + reg;
                if (rowg < N) {
                    float v = acc[r][c][reg] + bb;
                    if (isBF) P[((size_t)rowg << 7) + colg] = f2bf(v);
                    else      R[((size_t)rowg << 7) + (colg - 128)] = v;
                }
            }
        }
    }
}

// ---------------- agg2: out = mean_agg(P) + R ----------------
// Half-wave (32 lanes) per node, 8 nodes per block, 8x-unrolled gathers.
__global__ __launch_bounds__(256) void agg2_kernel(
    const unsigned short* __restrict__ P, const float* __restrict__ R,
    const int* __restrict__ cursor, const int* __restrict__ slots,
    float* __restrict__ out) {
    int node = blockIdx.x * 8 + (threadIdx.x >> 5);
    int l = threadIdx.x & 31;
    if (node >= NN) return;
    int deg = cursor[node];
    int degc = deg < CAP ? deg : CAP;
    const int* sl = slots + ((size_t)node << 6);
    float a0 = 0.f, a1 = 0.f, a2 = 0.f, a3 = 0.f;
    int i = 0;
    for (; i + 8 <= degc; i += 8) {
        uint2 v[8];
#pragma unroll
        for (int u = 0; u < 8; ++u) {
            int s = sl[i + u];
            v[u] = *(const uint2*)(P + ((size_t)s << 7) + l * 4);
        }
#pragma unroll
        for (int u = 0; u < 8; ++u) {
            a0 += bf_lo(v[u].x); a1 += bf_hi(v[u].x);
            a2 += bf_lo(v[u].y); a3 += bf_hi(v[u].y);
        }
    }
    for (; i < degc; ++i) {
        int s = sl[i];
        uint2 v = *(const uint2*)(P + ((size_t)s << 7) + l * 4);
        a0 += bf_lo(v.x); a1 += bf_hi(v.x);
        a2 += bf_lo(v.y); a3 += bf_hi(v.y);
    }
    float inv = 1.0f / (float)(deg > 1 ? deg : 1);
    float4 r4 = *(const float4*)(R + ((size_t)node << 7) + l * 4);
    float4 o;
    o.x = a0 * inv + r4.x;
    o.y = a1 * inv + r4.y;
    o.z = a2 * inv + r4.z;
    o.w = a3 * inv + r4.w;
    *(float4*)(out + ((size_t)node << 7) + l * 4) = o;
}

extern "C" void kernel_launch(void* const* d_in, const int* in_sizes, int n_in,
                              void* d_out, int out_size, void* d_ws, size_t ws_size,
                              hipStream_t stream) {
    const float* x    = (const float*)d_in[0];
    const int*   edges = (const int*)d_in[1];
    const float* W1_l = (const float*)d_in[2];
    const float* b1   = (const float*)d_in[3];
    const float* W1_r = (const float*)d_in[4];
    const float* W2_l = (const float*)d_in[5];
    const float* b2   = (const float*)d_in[6];
    const float* W2_r = (const float*)d_in[7];
    float* out = (float*)d_out;

    const int N = NN;
    auto al = [](size_t v) { return (v + 255) & ~(size_t)255; };
    char* ws = (char*)d_ws;
    size_t o = 0;
    int* flag   = (int*)(ws + o); o += 256;
    int* cursor = (int*)(ws + o); o += al((size_t)N * 4);
    int* slots  = (int*)(ws + o); o += al((size_t)N * CAP * 4);          // 12.8 MB
    unsigned short* x_bf = (unsigned short*)(ws + o); o += al((size_t)N * 128 * 2);
    unsigned short* h_bf = (unsigned short*)(ws + o); o += al((size_t)N * 256 * 2);
    unsigned short* P_bf = (unsigned short*)(ws + o); o += al((size_t)N * 128 * 2);
    float*          R_f  = (float*)(ws + o);          o += al((size_t)N * 128 * 4);
    unsigned short* B1   = (unsigned short*)(ws + o); o += al((size_t)256 * 256 * 2);
    unsigned short* B2   = (unsigned short*)(ws + o); o += al((size_t)256 * 256 * 2);

    // 1) prep: zero cursor + detect edge dtype
    prep_kernel<<<197, 256, 0, stream>>>(edges, cursor, flag);
    // 2) slot fill + packB + cast_x (single dispatch; fill blocks schedule first)
    fill_mega_kernel<<<FILL_NB + PACK_NB + CAST_NB, 256, 0, stream>>>(
        edges, flag, cursor, slots, x, W1_l, W1_r, W2_l, W2_r, x_bf, B1, B2);
    // 3) layer 1 fused: per-block mean-agg + GEMM + relu -> h (bf16)
    gemm1_fused_kernel<<<(N + 63) / 64, 256, 0, stream>>>(x_bf, cursor, slots, B1, b1, h_bf, N);
    // 4) layer 2 GEMM: [P||R] = h @ B2^T
    gemm2_kernel<<<(N + 63) / 64, 256, 0, stream>>>(h_bf, B2, b2, P_bf, R_f, N);
    // 5) out = mean_agg(P) + R
    agg2_kernel<<<(N + 7) / 8, 256, 0, stream>>>(P_bf, R_f, cursor, slots, out);
}

// Round 6
// 272.258 us; speedup vs baseline: 1.2424x; 1.2424x over previous
//
#include <hip/hip_runtime.h>
#include <stdint.h>

#define NN 50000
#define NE 800000
#define CAP 64   // slot capacity per node; P(Binom(800K,1/50K) >= 64) ~ 1e-30
// layer1: in=128 hid=256; layer2: in=256 out=128
// Layer-2 restructured: out = mean_agg(h @ W2_l^T) + (h @ W2_r^T + b2)
// CSR replaced by fixed-capacity slot table: slots[node][CAP], deg = cursor[node].
// R5 lesson: do NOT fuse the gather phase into the MFMA kernel (occupancy collapse).

typedef __bf16 bf16x8 __attribute__((ext_vector_type(8)));
typedef float  f32x4  __attribute__((ext_vector_type(4)));

__device__ __forceinline__ unsigned short f2bf(float f) {
    unsigned int u = __float_as_uint(f);
    unsigned int r = (u + 0x7fffu + ((u >> 16) & 1u)) >> 16;   // RNE
    return (unsigned short)r;
}
__device__ __forceinline__ float bf_lo(unsigned int v) { return __uint_as_float(v << 16); }
__device__ __forceinline__ float bf_hi(unsigned int v) { return __uint_as_float(v & 0xffff0000u); }

// ---------------- prep: zero cursor + detect edge dtype ----------------
__global__ __launch_bounds__(256) void prep_kernel(const int* __restrict__ edges,
                                                   int* __restrict__ cursor,
                                                   int* __restrict__ flag) {
    int b = blockIdx.x;
    if (b < 196) {
        int g = b * 256 + threadIdx.x;
        if (g < NN) cursor[g] = 0;
    } else {
        __shared__ int nz;
        if (threadIdx.x == 0) nz = 0;
        __syncthreads();
        for (int i = threadIdx.x; i < 512; i += 256)
            if (edges[2 * i + 1] != 0) atomicOr(&nz, 1);
        __syncthreads();
        if (threadIdx.x == 0) *flag = nz ? 0 : 1;  // 1 => int64 storage
    }
}

// ---------------- fill_mega: slot fill + cast_x + packB in one dispatch ----------------
// blocks [0,FILL_NB):                 fill slots (8 edges/thread, pipelined atomic chains)
// blocks [FILL_NB,FILL_NB+PACK_NB):   pack B1/B2 (131072 elems)
// rest:                               cast x f32->bf16 (float4 per thread)
#define FILL_NB 391
#define PACK_NB 512
#define CAST_NB 6250
__global__ __launch_bounds__(256) void fill_mega_kernel(
    const int* __restrict__ edges, const int* __restrict__ flag,
    int* __restrict__ cursor, int* __restrict__ slots,
    const float* __restrict__ x,
    const float* __restrict__ W1l, const float* __restrict__ W1r,
    const float* __restrict__ W2l, const float* __restrict__ W2r,
    unsigned short* __restrict__ x_bf,
    unsigned short* __restrict__ B1, unsigned short* __restrict__ B2) {
    int b = blockIdx.x;
    if (b < FILL_NB) {
        int f = *flag;
        int base = (b * 256 + threadIdx.x) * 8;
        const int E = NE;
        if (base + 8 <= E) {
            int s[8], d[8], pos[8];
#pragma unroll
            for (int u = 0; u < 8; ++u) {
                s[u] = edges[(size_t)(base + u) << f];
                d[u] = edges[(size_t)(E + base + u) << f];
            }
#pragma unroll
            for (int u = 0; u < 8; ++u) pos[u] = atomicAdd(&cursor[d[u]], 1);
#pragma unroll
            for (int u = 0; u < 8; ++u)
                if (pos[u] < CAP) slots[((size_t)d[u] << 6) + pos[u]] = s[u];
        } else {
            for (int e = base; e < E; ++e) {
                int s0 = edges[(size_t)e << f];
                int d0 = edges[(size_t)(E + e) << f];
                int p = atomicAdd(&cursor[d0], 1);
                if (p < CAP) slots[((size_t)d0 << 6) + p] = s0;
            }
        }
    } else if (b < FILL_NB + PACK_NB) {
        int idx = (b - FILL_NB) * 256 + threadIdx.x;   // 0..131071
        if (idx < 65536) {
            int o = idx >> 8, k = idx & 255;
            float v = (k < 128) ? W1l[o * 128 + k] : W1r[o * 128 + (k - 128)];
            B1[idx] = f2bf(v);
        } else {
            int j = idx - 65536;
            int o = j >> 8, k = j & 255;
            float v = (o < 128) ? W2l[o * 256 + k] : W2r[(o - 128) * 256 + k];
            B2[j] = f2bf(v);
        }
    } else {
        int i4 = (b - FILL_NB - PACK_NB) * 256 + threadIdx.x;  // one float4 each
        float4 v = *(const float4*)(x + (size_t)i4 * 4);
        uint2 p;
        p.x = (unsigned int)f2bf(v.x) | ((unsigned int)f2bf(v.y) << 16);
        p.y = (unsigned int)f2bf(v.z) | ((unsigned int)f2bf(v.w) << 16);
        *(uint2*)(x_bf + (size_t)i4 * 4) = p;
    }
}

// ---------------- agg1: mean1 = mean_agg(x_bf), width-128 bf16 rows ----------------
// Half-wave (32 lanes) per node, 8 nodes/block, 8x-unrolled gathers (16 in flight/wave).
__global__ __launch_bounds__(256) void agg1_kernel(
    const unsigned short* __restrict__ X, const int* __restrict__ cursor,
    const int* __restrict__ slots, unsigned short* __restrict__ mean) {
    int node = blockIdx.x * 8 + (threadIdx.x >> 5);
    int l = threadIdx.x & 31;
    if (node >= NN) return;
    int deg = cursor[node];
    int degc = deg < CAP ? deg : CAP;
    const int* sl = slots + ((size_t)node << 6);
    float a0 = 0.f, a1 = 0.f, a2 = 0.f, a3 = 0.f;
    int i = 0;
    for (; i + 8 <= degc; i += 8) {
        uint2 v[8];
#pragma unroll
        for (int u = 0; u < 8; ++u) {
            int s = sl[i + u];
            v[u] = *(const uint2*)(X + ((size_t)s << 7) + l * 4);
        }
#pragma unroll
        for (int u = 0; u < 8; ++u) {
            a0 += bf_lo(v[u].x); a1 += bf_hi(v[u].x);
            a2 += bf_lo(v[u].y); a3 += bf_hi(v[u].y);
        }
    }
    for (; i < degc; ++i) {
        int s = sl[i];
        uint2 v = *(const uint2*)(X + ((size_t)s << 7) + l * 4);
        a0 += bf_lo(v.x); a1 += bf_hi(v.x);
        a2 += bf_lo(v.y); a3 += bf_hi(v.y);
    }
    float inv = 1.0f / (float)(deg > 1 ? deg : 1);
    uint2 p;
    p.x = (unsigned int)f2bf(a0 * inv) | ((unsigned int)f2bf(a1 * inv) << 16);
    p.y = (unsigned int)f2bf(a2 * inv) | ((unsigned int)f2bf(a3 * inv) << 16);
    *(uint2*)(mean + ((size_t)node << 7) + l * 4) = p;
}

// ---------------- bf16 MFMA GEMM: 64 rows x 256 cols per block ----------------
// C[m,n] = sum_k A[m,k]*B[n,k] (+bias); A=[A1(K1)||A2(256-K1)] bf16, B[256][256] bf16.
// cols < split -> bf16 out (ld=split, opt relu, bias biasBF); else f32 out (+biasF).
#define LDK 72
__global__ __launch_bounds__(256) void gemm_mfma(
    const unsigned short* __restrict__ A1, const unsigned short* __restrict__ A2, int K1,
    const unsigned short* __restrict__ B,
    const float* __restrict__ biasBF, const float* __restrict__ biasF,
    unsigned short* __restrict__ outBF, float* __restrict__ outF,
    int N, int split, int reluBF) {
    __shared__ unsigned short As[64 * LDK];    // 9.0 KB
    __shared__ unsigned short Bs[256 * LDK];   // 36.0 KB
    int tid = threadIdx.x;
    int row0 = blockIdx.x * 64;
    int w = tid >> 6, lane = tid & 63;
    int q = lane >> 4, l16 = lane & 15;

    f32x4 acc[4][4];
#pragma unroll
    for (int r = 0; r < 4; ++r)
#pragma unroll
        for (int c = 0; c < 4; ++c) acc[r][c] = (f32x4){0.f, 0.f, 0.f, 0.f};
    const int K2 = 256 - K1;

    for (int ks = 0; ks < 4; ++ks) {
        int kbase = ks * 64;
        if (ks) __syncthreads();
#pragma unroll
        for (int i = 0; i < 2; ++i) {
            int lin = tid + 256 * i;
            int r = lin >> 3, g = lin & 7;
            int k = kbase + g * 8;
            uint4 av = make_uint4(0, 0, 0, 0);
            int grow = row0 + r;
            if (grow < N) {
                if (k < K1) av = *(const uint4*)(A1 + (size_t)grow * K1 + k);
                else        av = *(const uint4*)(A2 + (size_t)grow * K2 + (k - K1));
            }
            *(uint4*)&As[r * LDK + g * 8] = av;
        }
#pragma unroll
        for (int i = 0; i < 8; ++i) {
            int lin = tid + 256 * i;
            int n = lin >> 3, g = lin & 7;
            int k = kbase + g * 8;
            *(uint4*)&Bs[n * LDK + g * 8] = *(const uint4*)(B + ((size_t)n << 8) + k);
        }
        __syncthreads();
#pragma unroll
        for (int k0 = 0; k0 < 64; k0 += 32) {
            bf16x8 bfrag[4], afrag[4];
#pragma unroll
            for (int c = 0; c < 4; ++c)
                bfrag[c] = *(const bf16x8*)&Bs[(w * 64 + c * 16 + l16) * LDK + k0 + q * 8];
#pragma unroll
            for (int r = 0; r < 4; ++r)
                afrag[r] = *(const bf16x8*)&As[(r * 16 + l16) * LDK + k0 + q * 8];
#pragma unroll
            for (int r = 0; r < 4; ++r)
#pragma unroll
                for (int c = 0; c < 4; ++c)
                    acc[r][c] = __builtin_amdgcn_mfma_f32_16x16x32_bf16(afrag[r], bfrag[c], acc[r][c], 0, 0, 0);
        }
    }

    // epilogue: D col = lane&15, row = q*4 + reg
#pragma unroll
    for (int c = 0; c < 4; ++c) {
        int colg = w * 64 + c * 16 + l16;
        bool isBF = (colg < split);
        float bb = 0.f;
        if (isBF) { if (biasBF) bb = biasBF[colg]; }
        else      bb = biasF[colg - split];
#pragma unroll
        for (int r = 0; r < 4; ++r) {
#pragma unroll
            for (int reg = 0; reg < 4; ++reg) {
                int rowg = row0 + r * 16 + q * 4 + reg;
                if (rowg < N) {
                    float v = acc[r][c][reg] + bb;
                    if (isBF) {
                        if (reluBF) v = fmaxf(v, 0.f);
                        outBF[(size_t)rowg * split + colg] = f2bf(v);
                    } else {
                        outF[(size_t)rowg * (256 - split) + (colg - split)] = v;
                    }
                }
            }
        }
    }
}

// ---------------- agg2: out = mean_agg(P) + R ----------------
__global__ __launch_bounds__(256) void agg2_kernel(
    const unsigned short* __restrict__ P, const float* __restrict__ R,
    const int* __restrict__ cursor, const int* __restrict__ slots,
    float* __restrict__ out) {
    int node = blockIdx.x * 8 + (threadIdx.x >> 5);
    int l = threadIdx.x & 31;
    if (node >= NN) return;
    int deg = cursor[node];
    int degc = deg < CAP ? deg : CAP;
    const int* sl = slots + ((size_t)node << 6);
    float a0 = 0.f, a1 = 0.f, a2 = 0.f, a3 = 0.f;
    int i = 0;
    for (; i + 8 <= degc; i += 8) {
        uint2 v[8];
#pragma unroll
        for (int u = 0; u < 8; ++u) {
            int s = sl[i + u];
            v[u] = *(const uint2*)(P + ((size_t)s << 7) + l * 4);
        }
#pragma unroll
        for (int u = 0; u < 8; ++u) {
            a0 += bf_lo(v[u].x); a1 += bf_hi(v[u].x);
            a2 += bf_lo(v[u].y); a3 += bf_hi(v[u].y);
        }
    }
    for (; i < degc; ++i) {
        int s = sl[i];
        uint2 v = *(const uint2*)(P + ((size_t)s << 7) + l * 4);
        a0 += bf_lo(v.x); a1 += bf_hi(v.x);
        a2 += bf_lo(v.y); a3 += bf_hi(v.y);
    }
    float inv = 1.0f / (float)(deg > 1 ? deg : 1);
    float4 r4 = *(const float4*)(R + ((size_t)node << 7) + l * 4);
    float4 o;
    o.x = a0 * inv + r4.x;
    o.y = a1 * inv + r4.y;
    o.z = a2 * inv + r4.z;
    o.w = a3 * inv + r4.w;
    *(float4*)(out + ((size_t)node << 7) + l * 4) = o;
}

extern "C" void kernel_launch(void* const* d_in, const int* in_sizes, int n_in,
                              void* d_out, int out_size, void* d_ws, size_t ws_size,
                              hipStream_t stream) {
    const float* x    = (const float*)d_in[0];
    const int*   edges = (const int*)d_in[1];
    const float* W1_l = (const float*)d_in[2];
    const float* b1   = (const float*)d_in[3];
    const float* W1_r = (const float*)d_in[4];
    const float* W2_l = (const float*)d_in[5];
    const float* b2   = (const float*)d_in[6];
    const float* W2_r = (const float*)d_in[7];
    float* out = (float*)d_out;

    const int N = NN;
    auto al = [](size_t v) { return (v + 255) & ~(size_t)255; };
    char* ws = (char*)d_ws;
    size_t o = 0;
    int* flag   = (int*)(ws + o); o += 256;
    int* cursor = (int*)(ws + o); o += al((size_t)N * 4);
    int* slots  = (int*)(ws + o); o += al((size_t)N * CAP * 4);          // 12.8 MB
    unsigned short* x_bf  = (unsigned short*)(ws + o); o += al((size_t)N * 128 * 2);
    unsigned short* mean1 = (unsigned short*)(ws + o); o += al((size_t)N * 128 * 2);
    unsigned short* h_bf  = (unsigned short*)(ws + o); o += al((size_t)N * 256 * 2);
    unsigned short* P_bf  = (unsigned short*)(ws + o); o += al((size_t)N * 128 * 2);
    float*          R_f   = (float*)(ws + o);          o += al((size_t)N * 128 * 4);
    unsigned short* B1    = (unsigned short*)(ws + o); o += al((size_t)256 * 256 * 2);
    unsigned short* B2    = (unsigned short*)(ws + o); o += al((size_t)256 * 256 * 2);

    // 1) prep: zero cursor + detect edge dtype
    prep_kernel<<<197, 256, 0, stream>>>(edges, cursor, flag);
    // 2) slot fill + packB + cast_x (single dispatch; fill blocks schedule first)
    fill_mega_kernel<<<FILL_NB + PACK_NB + CAST_NB, 256, 0, stream>>>(
        edges, flag, cursor, slots, x, W1_l, W1_r, W2_l, W2_r, x_bf, B1, B2);
    // 3) mean1 = mean_agg(x_bf)
    agg1_kernel<<<(N + 7) / 8, 256, 0, stream>>>(x_bf, cursor, slots, mean1);
    // 4) h = relu([mean1||x_bf] @ B1^T + b1)  (bf16)
    gemm_mfma<<<(N + 63) / 64, 256, 0, stream>>>(mean1, x_bf, 128, B1, b1, b1,
                                                 h_bf, (float*)nullptr, N, 256, 1);
    // 5) [P||R] = h @ B2^T ; P bf16 (no bias), R f32 (+b2)
    gemm_mfma<<<(N + 63) / 64, 256, 0, stream>>>(h_bf, h_bf, 256, B2, (float*)nullptr, b2,
                                                 P_bf, R_f, N, 128, 0);
    // 6) out = mean_agg(P) + R
    agg2_kernel<<<(N + 7) / 8, 256, 0, stream>>>(P_bf, R_f, cursor, slots, out);
}

// Round 7
// 269.968 us; speedup vs baseline: 1.2529x; 1.0085x over previous
//
#include <hip/hip_runtime.h>
#include <stdint.h>

#define NN 50000
#define NE 800000
#define CAP 64   // slot capacity per node; P(Binom(800K,1/50K) >= 64) ~ 1e-30
#define CSTRIDE 16  // cursor padded to one counter per 64B line (kills false sharing)
// layer1: in=128 hid=256; layer2: in=256 out=128
// Layer-2 restructured: out = mean_agg(h @ W2_l^T) + (h @ W2_r^T + b2)
// R5 lesson: never fuse the gather phase into the MFMA kernel (occupancy collapse).
// R6 lesson: fill atomics were line-serialized (16 counters/line) -> pad cursor.

typedef __bf16 bf16x8 __attribute__((ext_vector_type(8)));
typedef float  f32x4  __attribute__((ext_vector_type(4)));

__device__ __forceinline__ unsigned short f2bf(float f) {
    unsigned int u = __float_as_uint(f);
    unsigned int r = (u + 0x7fffu + ((u >> 16) & 1u)) >> 16;   // RNE
    return (unsigned short)r;
}
__device__ __forceinline__ float bf_lo(unsigned int v) { return __uint_as_float(v << 16); }
__device__ __forceinline__ float bf_hi(unsigned int v) { return __uint_as_float(v & 0xffff0000u); }

// ---------------- fill_mega: slot fill + cast_x + packB in one dispatch ----------------
// blocks [0,FILL_NB):                 fill slots (8 edges/thread, pipelined atomic chains)
// blocks [FILL_NB,FILL_NB+PACK_NB):   pack B1/B2 (131072 elems)
// rest:                               cast x f32->bf16 (float4 per thread)
// Edge dtype (int64 vs int32 storage) detected per fill block: odd 32-bit words of the
// first 512 pairs are all-zero iff int64 little-endian with ids < 2^31.
#define FILL_NB 391
#define PACK_NB 512
#define CAST_NB 6250
__global__ __launch_bounds__(256) void fill_mega_kernel(
    const int* __restrict__ edges,
    int* __restrict__ cursor, int* __restrict__ slots,
    const float* __restrict__ x,
    const float* __restrict__ W1l, const float* __restrict__ W1r,
    const float* __restrict__ W2l, const float* __restrict__ W2r,
    unsigned short* __restrict__ x_bf,
    unsigned short* __restrict__ B1, unsigned short* __restrict__ B2) {
    int b = blockIdx.x;
    if (b < FILL_NB) {
        // per-block edge-dtype detect (512 pairs, L2-hot after first block)
        __shared__ int nz;
        if (threadIdx.x == 0) nz = 0;
        __syncthreads();
        int accv = 0;
        for (int i = threadIdx.x; i < 512; i += 256) accv |= edges[2 * i + 1];
        if (accv) atomicOr(&nz, 1);
        __syncthreads();
        int f = nz ? 0 : 1;   // 1 => int64 storage

        int base = (b * 256 + threadIdx.x) * 8;
        const int E = NE;
        if (base + 8 <= E) {
            int s[8], d[8], pos[8];
#pragma unroll
            for (int u = 0; u < 8; ++u) {
                s[u] = edges[(size_t)(base + u) << f];
                d[u] = edges[(size_t)(E + base + u) << f];
            }
#pragma unroll
            for (int u = 0; u < 8; ++u) pos[u] = atomicAdd(&cursor[(size_t)d[u] * CSTRIDE], 1);
#pragma unroll
            for (int u = 0; u < 8; ++u)
                if (pos[u] < CAP) slots[((size_t)d[u] << 6) + pos[u]] = s[u];
        } else {
            for (int e = base; e < E; ++e) {
                int s0 = edges[(size_t)e << f];
                int d0 = edges[(size_t)(E + e) << f];
                int p = atomicAdd(&cursor[(size_t)d0 * CSTRIDE], 1);
                if (p < CAP) slots[((size_t)d0 << 6) + p] = s0;
            }
        }
    } else if (b < FILL_NB + PACK_NB) {
        int idx = (b - FILL_NB) * 256 + threadIdx.x;   // 0..131071
        if (idx < 65536) {
            int o = idx >> 8, k = idx & 255;
            float v = (k < 128) ? W1l[o * 128 + k] : W1r[o * 128 + (k - 128)];
            B1[idx] = f2bf(v);
        } else {
            int j = idx - 65536;
            int o = j >> 8, k = j & 255;
            float v = (o < 128) ? W2l[o * 256 + k] : W2r[(o - 128) * 256 + k];
            B2[j] = f2bf(v);
        }
    } else {
        int i4 = (b - FILL_NB - PACK_NB) * 256 + threadIdx.x;  // one float4 each
        float4 v = *(const float4*)(x + (size_t)i4 * 4);
        uint2 p;
        p.x = (unsigned int)f2bf(v.x) | ((unsigned int)f2bf(v.y) << 16);
        p.y = (unsigned int)f2bf(v.z) | ((unsigned int)f2bf(v.w) << 16);
        *(uint2*)(x_bf + (size_t)i4 * 4) = p;
    }
}

// ---------------- agg1: mean1 = mean_agg(x_bf), width-128 bf16 rows ----------------
// Quarter-wave (16 lanes) per node: 16 lanes x 16B uint4 = 256B coalesced row,
// 4 independent gather chains per wave x 8 unroll = 32 outstanding loads/wave.
__global__ __launch_bounds__(256) void agg1_kernel(
    const unsigned short* __restrict__ X, const int* __restrict__ cursor,
    const int* __restrict__ slots, unsigned short* __restrict__ mean) {
    int node = blockIdx.x * 16 + (threadIdx.x >> 4);
    int l = threadIdx.x & 15;
    if (node >= NN) return;
    int deg = cursor[(size_t)node * CSTRIDE];
    int degc = deg < CAP ? deg : CAP;
    const int* sl = slots + ((size_t)node << 6);
    float a0 = 0.f, a1 = 0.f, a2 = 0.f, a3 = 0.f, a4 = 0.f, a5 = 0.f, a6 = 0.f, a7 = 0.f;
    int i = 0;
    for (; i + 8 <= degc; i += 8) {
        uint4 v[8];
#pragma unroll
        for (int u = 0; u < 8; ++u) {
            int s = sl[i + u];
            v[u] = *(const uint4*)(X + ((size_t)s << 7) + l * 8);
        }
#pragma unroll
        for (int u = 0; u < 8; ++u) {
            a0 += bf_lo(v[u].x); a1 += bf_hi(v[u].x);
            a2 += bf_lo(v[u].y); a3 += bf_hi(v[u].y);
            a4 += bf_lo(v[u].z); a5 += bf_hi(v[u].z);
            a6 += bf_lo(v[u].w); a7 += bf_hi(v[u].w);
        }
    }
    for (; i < degc; ++i) {
        int s = sl[i];
        uint4 v = *(const uint4*)(X + ((size_t)s << 7) + l * 8);
        a0 += bf_lo(v.x); a1 += bf_hi(v.x);
        a2 += bf_lo(v.y); a3 += bf_hi(v.y);
        a4 += bf_lo(v.z); a5 += bf_hi(v.z);
        a6 += bf_lo(v.w); a7 += bf_hi(v.w);
    }
    float inv = 1.0f / (float)(deg > 1 ? deg : 1);
    uint4 p;
    p.x = (unsigned int)f2bf(a0 * inv) | ((unsigned int)f2bf(a1 * inv) << 16);
    p.y = (unsigned int)f2bf(a2 * inv) | ((unsigned int)f2bf(a3 * inv) << 16);
    p.z = (unsigned int)f2bf(a4 * inv) | ((unsigned int)f2bf(a5 * inv) << 16);
    p.w = (unsigned int)f2bf(a6 * inv) | ((unsigned int)f2bf(a7 * inv) << 16);
    *(uint4*)(mean + ((size_t)node << 7) + l * 8) = p;
}

// ---------------- bf16 MFMA GEMM: 64 rows x 256 cols per block ----------------
// C[m,n] = sum_k A[m,k]*B[n,k] (+bias); A=[A1(K1)||A2(256-K1)] bf16, B[256][256] bf16.
// cols < split -> bf16 out (ld=split, opt relu, bias biasBF); else f32 out (+biasF).
#define LDK 72
__global__ __launch_bounds__(256) void gemm_mfma(
    const unsigned short* __restrict__ A1, const unsigned short* __restrict__ A2, int K1,
    const unsigned short* __restrict__ B,
    const float* __restrict__ biasBF, const float* __restrict__ biasF,
    unsigned short* __restrict__ outBF, float* __restrict__ outF,
    int N, int split, int reluBF) {
    __shared__ unsigned short As[64 * LDK];    // 9.0 KB
    __shared__ unsigned short Bs[256 * LDK];   // 36.0 KB
    int tid = threadIdx.x;
    int row0 = blockIdx.x * 64;
    int w = tid >> 6, lane = tid & 63;
    int q = lane >> 4, l16 = lane & 15;

    f32x4 acc[4][4];
#pragma unroll
    for (int r = 0; r < 4; ++r)
#pragma unroll
        for (int c = 0; c < 4; ++c) acc[r][c] = (f32x4){0.f, 0.f, 0.f, 0.f};
    const int K2 = 256 - K1;

    for (int ks = 0; ks < 4; ++ks) {
        int kbase = ks * 64;
        if (ks) __syncthreads();
#pragma unroll
        for (int i = 0; i < 2; ++i) {
            int lin = tid + 256 * i;
            int r = lin >> 3, g = lin & 7;
            int k = kbase + g * 8;
            uint4 av = make_uint4(0, 0, 0, 0);
            int grow = row0 + r;
            if (grow < N) {
                if (k < K1) av = *(const uint4*)(A1 + (size_t)grow * K1 + k);
                else        av = *(const uint4*)(A2 + (size_t)grow * K2 + (k - K1));
            }
            *(uint4*)&As[r * LDK + g * 8] = av;
        }
#pragma unroll
        for (int i = 0; i < 8; ++i) {
            int lin = tid + 256 * i;
            int n = lin >> 3, g = lin & 7;
            int k = kbase + g * 8;
            *(uint4*)&Bs[n * LDK + g * 8] = *(const uint4*)(B + ((size_t)n << 8) + k);
        }
        __syncthreads();
#pragma unroll
        for (int k0 = 0; k0 < 64; k0 += 32) {
            bf16x8 bfrag[4], afrag[4];
#pragma unroll
            for (int c = 0; c < 4; ++c)
                bfrag[c] = *(const bf16x8*)&Bs[(w * 64 + c * 16 + l16) * LDK + k0 + q * 8];
#pragma unroll
            for (int r = 0; r < 4; ++r)
                afrag[r] = *(const bf16x8*)&As[(r * 16 + l16) * LDK + k0 + q * 8];
#pragma unroll
            for (int r = 0; r < 4; ++r)
#pragma unroll
                for (int c = 0; c < 4; ++c)
                    acc[r][c] = __builtin_amdgcn_mfma_f32_16x16x32_bf16(afrag[r], bfrag[c], acc[r][c], 0, 0, 0);
        }
    }

    // epilogue: D col = lane&15, row = q*4 + reg
#pragma unroll
    for (int c = 0; c < 4; ++c) {
        int colg = w * 64 + c * 16 + l16;
        bool isBF = (colg < split);
        float bb = 0.f;
        if (isBF) { if (biasBF) bb = biasBF[colg]; }
        else      bb = biasF[colg - split];
#pragma unroll
        for (int r = 0; r < 4; ++r) {
#pragma unroll
            for (int reg = 0; reg < 4; ++reg) {
                int rowg = row0 + r * 16 + q * 4 + reg;
                if (rowg < N) {
                    float v = acc[r][c][reg] + bb;
                    if (isBF) {
                        if (reluBF) v = fmaxf(v, 0.f);
                        outBF[(size_t)rowg * split + colg] = f2bf(v);
                    } else {
                        outF[(size_t)rowg * (256 - split) + (colg - split)] = v;
                    }
                }
            }
        }
    }
}

// ---------------- agg2: out = mean_agg(P) + R ----------------
// Quarter-wave per node (same MLP structure as agg1); R/out rows are 512B:
// lane l handles floats [l*8, l*8+8).
__global__ __launch_bounds__(256) void agg2_kernel(
    const unsigned short* __restrict__ P, const float* __restrict__ R,
    const int* __restrict__ cursor, const int* __restrict__ slots,
    float* __restrict__ out) {
    int node = blockIdx.x * 16 + (threadIdx.x >> 4);
    int l = threadIdx.x & 15;
    if (node >= NN) return;
    int deg = cursor[(size_t)node * CSTRIDE];
    int degc = deg < CAP ? deg : CAP;
    const int* sl = slots + ((size_t)node << 6);
    float a0 = 0.f, a1 = 0.f, a2 = 0.f, a3 = 0.f, a4 = 0.f, a5 = 0.f, a6 = 0.f, a7 = 0.f;
    int i = 0;
    for (; i + 8 <= degc; i += 8) {
        uint4 v[8];
#pragma unroll
        for (int u = 0; u < 8; ++u) {
            int s = sl[i + u];
            v[u] = *(const uint4*)(P + ((size_t)s << 7) + l * 8);
        }
#pragma unroll
        for (int u = 0; u < 8; ++u) {
            a0 += bf_lo(v[u].x); a1 += bf_hi(v[u].x);
            a2 += bf_lo(v[u].y); a3 += bf_hi(v[u].y);
            a4 += bf_lo(v[u].z); a5 += bf_hi(v[u].z);
            a6 += bf_lo(v[u].w); a7 += bf_hi(v[u].w);
        }
    }
    for (; i < degc; ++i) {
        int s = sl[i];
        uint4 v = *(const uint4*)(P + ((size_t)s << 7) + l * 8);
        a0 += bf_lo(v.x); a1 += bf_hi(v.x);
        a2 += bf_lo(v.y); a3 += bf_hi(v.y);
        a4 += bf_lo(v.z); a5 += bf_hi(v.z);
        a6 += bf_lo(v.w); a7 += bf_hi(v.w);
    }
    float inv = 1.0f / (float)(deg > 1 ? deg : 1);
    const float* rrow = R + ((size_t)node << 7) + l * 8;
    float4 r0 = *(const float4*)rrow;
    float4 r1 = *(const float4*)(rrow + 4);
    float4 o0, o1;
    o0.x = a0 * inv + r0.x; o0.y = a1 * inv + r0.y;
    o0.z = a2 * inv + r0.z; o0.w = a3 * inv + r0.w;
    o1.x = a4 * inv + r1.x; o1.y = a5 * inv + r1.y;
    o1.z = a6 * inv + r1.z; o1.w = a7 * inv + r1.w;
    float* orow = out + ((size_t)node << 7) + l * 8;
    *(float4*)orow = o0;
    *(float4*)(orow + 4) = o1;
}

extern "C" void kernel_launch(void* const* d_in, const int* in_sizes, int n_in,
                              void* d_out, int out_size, void* d_ws, size_t ws_size,
                              hipStream_t stream) {
    const float* x    = (const float*)d_in[0];
    const int*   edges = (const int*)d_in[1];
    const float* W1_l = (const float*)d_in[2];
    const float* b1   = (const float*)d_in[3];
    const float* W1_r = (const float*)d_in[4];
    const float* W2_l = (const float*)d_in[5];
    const float* b2   = (const float*)d_in[6];
    const float* W2_r = (const float*)d_in[7];
    float* out = (float*)d_out;

    const int N = NN;
    auto al = [](size_t v) { return (v + 255) & ~(size_t)255; };
    char* ws = (char*)d_ws;
    size_t o = 0;
    int* cursor = (int*)(ws + o); o += al((size_t)N * CSTRIDE * 4);      // 3.2 MB padded
    int* slots  = (int*)(ws + o); o += al((size_t)N * CAP * 4);          // 12.8 MB
    unsigned short* x_bf  = (unsigned short*)(ws + o); o += al((size_t)N * 128 * 2);
    unsigned short* mean1 = (unsigned short*)(ws + o); o += al((size_t)N * 128 * 2);
    unsigned short* h_bf  = (unsigned short*)(ws + o); o += al((size_t)N * 256 * 2);
    unsigned short* P_bf  = (unsigned short*)(ws + o); o += al((size_t)N * 128 * 2);
    float*          R_f   = (float*)(ws + o);          o += al((size_t)N * 128 * 4);
    unsigned short* B1    = (unsigned short*)(ws + o); o += al((size_t)256 * 256 * 2);
    unsigned short* B2    = (unsigned short*)(ws + o); o += al((size_t)256 * 256 * 2);

    // 1) zero padded cursor
    hipMemsetAsync(cursor, 0, (size_t)N * CSTRIDE * 4, stream);
    // 2) slot fill (per-block dtype detect) + packB + cast_x in one dispatch
    fill_mega_kernel<<<FILL_NB + PACK_NB + CAST_NB, 256, 0, stream>>>(
        edges, cursor, slots, x, W1_l, W1_r, W2_l, W2_r, x_bf, B1, B2);
    // 3) mean1 = mean_agg(x_bf)
    agg1_kernel<<<(N + 15) / 16, 256, 0, stream>>>(x_bf, cursor, slots, mean1);
    // 4) h = relu([mean1||x_bf] @ B1^T + b1)  (bf16)
    gemm_mfma<<<(N + 63) / 64, 256, 0, stream>>>(mean1, x_bf, 128, B1, b1, b1,
                                                 h_bf, (float*)nullptr, N, 256, 1);
    // 5) [P||R] = h @ B2^T ; P bf16 (no bias), R f32 (+b2)
    gemm_mfma<<<(N + 63) / 64, 256, 0, stream>>>(h_bf, h_bf, 256, B2, (float*)nullptr, b2,
                                                 P_bf, R_f, N, 128, 0);
    // 6) out = mean_agg(P) + R
    agg2_kernel<<<(N + 15) / 16, 256, 0, stream>>>(P_bf, R_f, cursor, slots, out);
}

// Round 8
// 257.001 us; speedup vs baseline: 1.3161x; 1.0505x over previous
//
#include <hip/hip_runtime.h>
#include <stdint.h>

#define NN 50000
#define NE 800000
#define NBK 512          // dst buckets
#define NPB 98           // nodes per bucket (512*98 = 50176 >= 50000)
#define BUCKCAP 2048     // edges per bucket region; mean 1568, sigma ~40 -> 12 sigma margin
// layer1: in=128 hid=256; layer2: in=256 out=128
// Layer-2 restructured: out = mean_agg(h @ W2_l^T) + (h @ W2_r^T + b2)
// R5 lesson: never fuse the gather phase into the MFMA kernel (occupancy collapse).
// R7 lesson: 800K scatter atomics+stores are op-count-bound (~19G/s) -> reduce the count:
//   bucketed 2-pass build: per-block LDS sort -> ~200K atomics, coalesced run writes.

typedef __bf16 bf16x8 __attribute__((ext_vector_type(8)));
typedef float  f32x4  __attribute__((ext_vector_type(4)));

__device__ __forceinline__ unsigned short f2bf(float f) {
    unsigned int u = __float_as_uint(f);
    unsigned int r = (u + 0x7fffu + ((u >> 16) & 1u)) >> 16;   // RNE
    return (unsigned short)r;
}
__device__ __forceinline__ float bf_lo(unsigned int v) { return __uint_as_float(v << 16); }
__device__ __forceinline__ float bf_hi(unsigned int v) { return __uint_as_float(v & 0xffff0000u); }

// ---------------- mega: bucket bin-scatter + cast_x + packB in one dispatch ----------------
// blocks [0,FILL_NB):  pass1 bin-scatter (2048 edges/block, LDS sort by bucket)
// next PACK_NB:        pack B1/B2
// rest:                cast x f32->bf16
#define FILL_NB 391
#define PACK_NB 512
#define CAST_NB 6250
__global__ __launch_bounds__(256) void mega_kernel(
    const int* __restrict__ edges,
    int* __restrict__ bcur, unsigned int* __restrict__ packed,
    const float* __restrict__ x,
    const float* __restrict__ W1l, const float* __restrict__ W1r,
    const float* __restrict__ W2l, const float* __restrict__ W2r,
    unsigned short* __restrict__ x_bf,
    unsigned short* __restrict__ B1, unsigned short* __restrict__ B2) {
    __shared__ int hist[NBK];
    __shared__ int scn[NBK];
    __shared__ int gbase[NBK];
    __shared__ int lcur[NBK];
    __shared__ int ps[256];
    __shared__ unsigned int sortbuf[2048];
    __shared__ int gaddrbuf[2048];
    __shared__ int nz;
    int b = blockIdx.x;
    int t = threadIdx.x;
    if (b < FILL_NB) {
        const int E = NE;
        // edge dtype detect: odd words of first 512 pairs all zero <=> int64 storage
        if (t == 0) nz = 0;
        hist[t] = 0; hist[t + 256] = 0;
        __syncthreads();
        int accv = 0;
        for (int i = t; i < 512; i += 256) accv |= edges[2 * i + 1];
        if (accv) atomicOr(&nz, 1);
        __syncthreads();
        int f = nz ? 0 : 1;   // 1 => int64 storage

        int blockbase = b * 2048;
        int nedge = E - blockbase; if (nedge > 2048) nedge = 2048;
        unsigned int pk[8]; int bk[8];
#pragma unroll
        for (int u = 0; u < 8; ++u) {
            int lin = u * 256 + t;
            bk[u] = -1;
            if (lin < nedge) {
                int e = blockbase + lin;
                int src = edges[(size_t)e << f];
                int dst = edges[(size_t)(E + e) << f];
                int bb = dst / NPB;
                pk[u] = (unsigned int)src | ((unsigned int)(dst - bb * NPB) << 16);
                bk[u] = bb;
                atomicAdd(&hist[bb], 1);
            }
        }
        __syncthreads();
        // exclusive scan of hist[512] via 256-thread pair scan
        int h0 = hist[2 * t], h1 = hist[2 * t + 1];
        int s = h0 + h1;
        ps[t] = s;
        __syncthreads();
        for (int off = 1; off < 256; off <<= 1) {
            int v = (t >= off) ? ps[t - off] : 0;
            __syncthreads();
            ps[t] += v;
            __syncthreads();
        }
        int excl = ps[t] - s;
        scn[2 * t] = excl;
        scn[2 * t + 1] = excl + h0;
        // reserve global space per bucket (one atomic per non-empty bucket)
        if (h0) gbase[2 * t] = atomicAdd(&bcur[2 * t], h0);
        if (h1) gbase[2 * t + 1] = atomicAdd(&bcur[2 * t + 1], h1);
        lcur[2 * t] = excl;
        lcur[2 * t + 1] = excl + h0;
        __syncthreads();
        // place edges into LDS in bucket order, record global addresses
#pragma unroll
        for (int u = 0; u < 8; ++u) {
            if (bk[u] >= 0) {
                int p = atomicAdd(&lcur[bk[u]], 1);
                sortbuf[p] = pk[u];
                int off = gbase[bk[u]] + (p - scn[bk[u]]);
                gaddrbuf[p] = (off < BUCKCAP) ? (bk[u] * BUCKCAP + off) : -1;
            }
        }
        __syncthreads();
        // copy out: consecutive j -> consecutive addresses within runs (coalesced)
        for (int j = t; j < nedge; j += 256) {
            int a = gaddrbuf[j];
            if (a >= 0) packed[a] = sortbuf[j];
        }
    } else if (b < FILL_NB + PACK_NB) {
        int idx = (b - FILL_NB) * 256 + t;   // 0..131071
        if (idx < 65536) {
            int o = idx >> 8, k = idx & 255;
            float v = (k < 128) ? W1l[o * 128 + k] : W1r[o * 128 + (k - 128)];
            B1[idx] = f2bf(v);
        } else {
            int j = idx - 65536;
            int o = j >> 8, k = j & 255;
            float v = (o < 128) ? W2l[o * 256 + k] : W2r[(o - 128) * 256 + k];
            B2[j] = f2bf(v);
        }
    } else {
        int i4 = (b - FILL_NB - PACK_NB) * 256 + t;  // one float4 each
        float4 v = *(const float4*)(x + (size_t)i4 * 4);
        uint2 p;
        p.x = (unsigned int)f2bf(v.x) | ((unsigned int)f2bf(v.y) << 16);
        p.y = (unsigned int)f2bf(v.z) | ((unsigned int)f2bf(v.w) << 16);
        *(uint2*)(x_bf + (size_t)i4 * 4) = p;
    }
}

// ---------------- pass2: per-bucket counting sort -> per-node neighbor lists ----------------
// One block per bucket. All traffic L2-resident (~8KB packed window per bucket).
__global__ __launch_bounds__(256) void pass2_kernel(
    const unsigned int* __restrict__ packed, const int* __restrict__ bcur,
    int* __restrict__ nbr, int* __restrict__ row_start, int* __restrict__ deg) {
    __shared__ int hist[NPB];
    __shared__ int scn[NPB];
    __shared__ int lcur[NPB];
    int b = blockIdx.x;
    int t = threadIdx.x;
    int ne = bcur[b]; if (ne > BUCKCAP) ne = BUCKCAP;
    if (t < NPB) hist[t] = 0;
    __syncthreads();
    const unsigned int* pb = packed + (size_t)b * BUCKCAP;
    for (int j = t; j < ne; j += 256) atomicAdd(&hist[pb[j] >> 16], 1);
    __syncthreads();
    if (t == 0) {
        int a = 0;
        for (int i = 0; i < NPB; ++i) { scn[i] = a; a += hist[i]; }
    }
    __syncthreads();
    if (t < NPB) lcur[t] = scn[t];
    __syncthreads();
    for (int j = t; j < ne; j += 256) {
        unsigned int w = pb[j];
        int p = atomicAdd(&lcur[w >> 16], 1);
        nbr[(size_t)b * BUCKCAP + p] = (int)(w & 0xffffu);
    }
    if (t < NPB) {
        int node = b * NPB + t;
        if (node < NN) {
            row_start[node] = b * BUCKCAP + scn[t];
            deg[node] = hist[t];
        }
    }
}

// ---------------- agg1: mean1 = mean_agg(x_bf), width-128 bf16 rows ----------------
// Quarter-wave (16 lanes) per node: 16 x 16B uint4 = 256B coalesced row,
// 4 independent gather chains per wave x 8 unroll = 32 outstanding loads/wave.
__global__ __launch_bounds__(256) void agg1_kernel(
    const unsigned short* __restrict__ X, const int* __restrict__ row_start,
    const int* __restrict__ deg, const int* __restrict__ nbr,
    unsigned short* __restrict__ mean) {
    int node = blockIdx.x * 16 + (threadIdx.x >> 4);
    int l = threadIdx.x & 15;
    if (node >= NN) return;
    int dg = deg[node];
    const int* sl = nbr + row_start[node];
    float a0 = 0.f, a1 = 0.f, a2 = 0.f, a3 = 0.f, a4 = 0.f, a5 = 0.f, a6 = 0.f, a7 = 0.f;
    int i = 0;
    for (; i + 8 <= dg; i += 8) {
        uint4 v[8];
#pragma unroll
        for (int u = 0; u < 8; ++u) {
            int s = sl[i + u];
            v[u] = *(const uint4*)(X + ((size_t)s << 7) + l * 8);
        }
#pragma unroll
        for (int u = 0; u < 8; ++u) {
            a0 += bf_lo(v[u].x); a1 += bf_hi(v[u].x);
            a2 += bf_lo(v[u].y); a3 += bf_hi(v[u].y);
            a4 += bf_lo(v[u].z); a5 += bf_hi(v[u].z);
            a6 += bf_lo(v[u].w); a7 += bf_hi(v[u].w);
        }
    }
    for (; i < dg; ++i) {
        int s = sl[i];
        uint4 v = *(const uint4*)(X + ((size_t)s << 7) + l * 8);
        a0 += bf_lo(v.x); a1 += bf_hi(v.x);
        a2 += bf_lo(v.y); a3 += bf_hi(v.y);
        a4 += bf_lo(v.z); a5 += bf_hi(v.z);
        a6 += bf_lo(v.w); a7 += bf_hi(v.w);
    }
    float inv = 1.0f / (float)(dg > 1 ? dg : 1);
    uint4 p;
    p.x = (unsigned int)f2bf(a0 * inv) | ((unsigned int)f2bf(a1 * inv) << 16);
    p.y = (unsigned int)f2bf(a2 * inv) | ((unsigned int)f2bf(a3 * inv) << 16);
    p.z = (unsigned int)f2bf(a4 * inv) | ((unsigned int)f2bf(a5 * inv) << 16);
    p.w = (unsigned int)f2bf(a6 * inv) | ((unsigned int)f2bf(a7 * inv) << 16);
    *(uint4*)(mean + ((size_t)node << 7) + l * 8) = p;
}

// ---------------- bf16 MFMA GEMM: 64 rows x 256 cols per block (unchanged) ----------------
#define LDK 72
__global__ __launch_bounds__(256) void gemm_mfma(
    const unsigned short* __restrict__ A1, const unsigned short* __restrict__ A2, int K1,
    const unsigned short* __restrict__ B,
    const float* __restrict__ biasBF, const float* __restrict__ biasF,
    unsigned short* __restrict__ outBF, float* __restrict__ outF,
    int N, int split, int reluBF) {
    __shared__ unsigned short As[64 * LDK];    // 9.0 KB
    __shared__ unsigned short Bs[256 * LDK];   // 36.0 KB
    int tid = threadIdx.x;
    int row0 = blockIdx.x * 64;
    int w = tid >> 6, lane = tid & 63;
    int q = lane >> 4, l16 = lane & 15;

    f32x4 acc[4][4];
#pragma unroll
    for (int r = 0; r < 4; ++r)
#pragma unroll
        for (int c = 0; c < 4; ++c) acc[r][c] = (f32x4){0.f, 0.f, 0.f, 0.f};
    const int K2 = 256 - K1;

    for (int ks = 0; ks < 4; ++ks) {
        int kbase = ks * 64;
        if (ks) __syncthreads();
#pragma unroll
        for (int i = 0; i < 2; ++i) {
            int lin = tid + 256 * i;
            int r = lin >> 3, g = lin & 7;
            int k = kbase + g * 8;
            uint4 av = make_uint4(0, 0, 0, 0);
            int grow = row0 + r;
            if (grow < N) {
                if (k < K1) av = *(const uint4*)(A1 + (size_t)grow * K1 + k);
                else        av = *(const uint4*)(A2 + (size_t)grow * K2 + (k - K1));
            }
            *(uint4*)&As[r * LDK + g * 8] = av;
        }
#pragma unroll
        for (int i = 0; i < 8; ++i) {
            int lin = tid + 256 * i;
            int n = lin >> 3, g = lin & 7;
            int k = kbase + g * 8;
            *(uint4*)&Bs[n * LDK + g * 8] = *(const uint4*)(B + ((size_t)n << 8) + k);
        }
        __syncthreads();
#pragma unroll
        for (int k0 = 0; k0 < 64; k0 += 32) {
            bf16x8 bfrag[4], afrag[4];
#pragma unroll
            for (int c = 0; c < 4; ++c)
                bfrag[c] = *(const bf16x8*)&Bs[(w * 64 + c * 16 + l16) * LDK + k0 + q * 8];
#pragma unroll
            for (int r = 0; r < 4; ++r)
                afrag[r] = *(const bf16x8*)&As[(r * 16 + l16) * LDK + k0 + q * 8];
#pragma unroll
            for (int r = 0; r < 4; ++r)
#pragma unroll
                for (int c = 0; c < 4; ++c)
                    acc[r][c] = __builtin_amdgcn_mfma_f32_16x16x32_bf16(afrag[r], bfrag[c], acc[r][c], 0, 0, 0);
        }
    }

    // epilogue: D col = lane&15, row = q*4 + reg
#pragma unroll
    for (int c = 0; c < 4; ++c) {
        int colg = w * 64 + c * 16 + l16;
        bool isBF = (colg < split);
        float bb = 0.f;
        if (isBF) { if (biasBF) bb = biasBF[colg]; }
        else      bb = biasF[colg - split];
#pragma unroll
        for (int r = 0; r < 4; ++r) {
#pragma unroll
            for (int reg = 0; reg < 4; ++reg) {
                int rowg = row0 + r * 16 + q * 4 + reg;
                if (rowg < N) {
                    float v = acc[r][c][reg] + bb;
                    if (isBF) {
                        if (reluBF) v = fmaxf(v, 0.f);
                        outBF[(size_t)rowg * split + colg] = f2bf(v);
                    } else {
                        outF[(size_t)rowg * (256 - split) + (colg - split)] = v;
                    }
                }
            }
        }
    }
}

// ---------------- agg2: out = mean_agg(P) + R ----------------
__global__ __launch_bounds__(256) void agg2_kernel(
    const unsigned short* __restrict__ P, const float* __restrict__ R,
    const int* __restrict__ row_start, const int* __restrict__ deg,
    const int* __restrict__ nbr, float* __restrict__ out) {
    int node = blockIdx.x * 16 + (threadIdx.x >> 4);
    int l = threadIdx.x & 15;
    if (node >= NN) return;
    int dg = deg[node];
    const int* sl = nbr + row_start[node];
    float a0 = 0.f, a1 = 0.f, a2 = 0.f, a3 = 0.f, a4 = 0.f, a5 = 0.f, a6 = 0.f, a7 = 0.f;
    int i = 0;
    for (; i + 8 <= dg; i += 8) {
        uint4 v[8];
#pragma unroll
        for (int u = 0; u < 8; ++u) {
            int s = sl[i + u];
            v[u] = *(const uint4*)(P + ((size_t)s << 7) + l * 8);
        }
#pragma unroll
        for (int u = 0; u < 8; ++u) {
            a0 += bf_lo(v[u].x); a1 += bf_hi(v[u].x);
            a2 += bf_lo(v[u].y); a3 += bf_hi(v[u].y);
            a4 += bf_lo(v[u].z); a5 += bf_hi(v[u].z);
            a6 += bf_lo(v[u].w); a7 += bf_hi(v[u].w);
        }
    }
    for (; i < dg; ++i) {
        int s = sl[i];
        uint4 v = *(const uint4*)(P + ((size_t)s << 7) + l * 8);
        a0 += bf_lo(v.x); a1 += bf_hi(v.x);
        a2 += bf_lo(v.y); a3 += bf_hi(v.y);
        a4 += bf_lo(v.z); a5 += bf_hi(v.z);
        a6 += bf_lo(v.w); a7 += bf_hi(v.w);
    }
    float inv = 1.0f / (float)(dg > 1 ? dg : 1);
    const float* rrow = R + ((size_t)node << 7) + l * 8;
    float4 r0 = *(const float4*)rrow;
    float4 r1 = *(const float4*)(rrow + 4);
    float4 o0, o1;
    o0.x = a0 * inv + r0.x; o0.y = a1 * inv + r0.y;
    o0.z = a2 * inv + r0.z; o0.w = a3 * inv + r0.w;
    o1.x = a4 * inv + r1.x; o1.y = a5 * inv + r1.y;
    o1.z = a6 * inv + r1.z; o1.w = a7 * inv + r1.w;
    float* orow = out + ((size_t)node << 7) + l * 8;
    *(float4*)orow = o0;
    *(float4*)(orow + 4) = o1;
}

extern "C" void kernel_launch(void* const* d_in, const int* in_sizes, int n_in,
                              void* d_out, int out_size, void* d_ws, size_t ws_size,
                              hipStream_t stream) {
    const float* x    = (const float*)d_in[0];
    const int*   edges = (const int*)d_in[1];
    const float* W1_l = (const float*)d_in[2];
    const float* b1   = (const float*)d_in[3];
    const float* W1_r = (const float*)d_in[4];
    const float* W2_l = (const float*)d_in[5];
    const float* b2   = (const float*)d_in[6];
    const float* W2_r = (const float*)d_in[7];
    float* out = (float*)d_out;

    const int N = NN;
    auto al = [](size_t v) { return (v + 255) & ~(size_t)255; };
    char* ws = (char*)d_ws;
    size_t o = 0;
    int* bcur = (int*)(ws + o); o += al((size_t)NBK * 4);
    unsigned int* packed = (unsigned int*)(ws + o); o += al((size_t)NBK * BUCKCAP * 4);  // 4 MB
    int* nbr       = (int*)(ws + o); o += al((size_t)NBK * BUCKCAP * 4);                 // 4 MB
    int* row_start = (int*)(ws + o); o += al((size_t)N * 4);
    int* deg       = (int*)(ws + o); o += al((size_t)N * 4);
    unsigned short* x_bf  = (unsigned short*)(ws + o); o += al((size_t)N * 128 * 2);
    unsigned short* mean1 = (unsigned short*)(ws + o); o += al((size_t)N * 128 * 2);
    unsigned short* h_bf  = (unsigned short*)(ws + o); o += al((size_t)N * 256 * 2);
    unsigned short* P_bf  = (unsigned short*)(ws + o); o += al((size_t)N * 128 * 2);
    float*          R_f   = (float*)(ws + o);          o += al((size_t)N * 128 * 4);
    unsigned short* B1    = (unsigned short*)(ws + o); o += al((size_t)256 * 256 * 2);
    unsigned short* B2    = (unsigned short*)(ws + o); o += al((size_t)256 * 256 * 2);

    // 1) zero bucket cursors (2 KB)
    hipMemsetAsync(bcur, 0, (size_t)NBK * 4, stream);
    // 2) bin-scatter + packB + cast_x in one dispatch
    mega_kernel<<<FILL_NB + PACK_NB + CAST_NB, 256, 0, stream>>>(
        edges, bcur, packed, x, W1_l, W1_r, W2_l, W2_r, x_bf, B1, B2);
    // 3) per-bucket counting sort -> nbr / row_start / deg
    pass2_kernel<<<NBK, 256, 0, stream>>>(packed, bcur, nbr, row_start, deg);
    // 4) mean1 = mean_agg(x_bf)
    agg1_kernel<<<(N + 15) / 16, 256, 0, stream>>>(x_bf, row_start, deg, nbr, mean1);
    // 5) h = relu([mean1||x_bf] @ B1^T + b1)  (bf16)
    gemm_mfma<<<(N + 63) / 64, 256, 0, stream>>>(mean1, x_bf, 128, B1, b1, b1,
                                                 h_bf, (float*)nullptr, N, 256, 1);
    // 6) [P||R] = h @ B2^T ; P bf16 (no bias), R f32 (+b2)
    gemm_mfma<<<(N + 63) / 64, 256, 0, stream>>>(h_bf, h_bf, 256, B2, (float*)nullptr, b2,
                                                 P_bf, R_f, N, 128, 0);
    // 7) out = mean_agg(P) + R
    agg2_kernel<<<(N + 15) / 16, 256, 0, stream>>>(P_bf, R_f, row_start, deg, nbr, out);
}

// Round 9
// 251.541 us; speedup vs baseline: 1.3447x; 1.0217x over previous
//
#include <hip/hip_runtime.h>
#include <stdint.h>

#define NN 50000
#define NE 800000
#define NBK 512          // dst buckets
#define NPB 98           // nodes per bucket (512*98 = 50176 >= 50000)
#define BUCKCAP 2048     // edges per bucket region; mean 1568 -> 12 sigma margin
// layer1: in=128 hid=256; layer2: in=256 out=128
// Layer-2 restructured: out = mean_agg(h @ W2_l^T) + (h @ W2_r^T + b2)
// R5: never fuse gather phase into MFMA kernel. R7: scatter atomics op-count-bound.
// R8 lesson: VGPR-round-trip LDS staging stalls the GEMM 6x above roofline ->
//   global_load_lds(16B) + XOR-swizzled unpadded LDS (m97 recipe).

typedef __bf16 bf16x8 __attribute__((ext_vector_type(8)));
typedef float  f32x4  __attribute__((ext_vector_type(4)));

__device__ __forceinline__ unsigned short f2bf(float f) {
    unsigned int u = __float_as_uint(f);
    unsigned int r = (u + 0x7fffu + ((u >> 16) & 1u)) >> 16;   // RNE
    return (unsigned short)r;
}
__device__ __forceinline__ float bf_lo(unsigned int v) { return __uint_as_float(v << 16); }
__device__ __forceinline__ float bf_hi(unsigned int v) { return __uint_as_float(v & 0xffff0000u); }

// async global->LDS, 16 B per lane; lds base wave-uniform, lane i lands at base+16i
__device__ __forceinline__ void gl_lds16(const void* g, void* l) {
    __builtin_amdgcn_global_load_lds(
        (const __attribute__((address_space(1))) void*)g,
        (__attribute__((address_space(3))) void*)l, 16, 0, 0);
}

// ---------------- mega: bucket bin-scatter + cast_x + packB in one dispatch ----------------
#define FILL_NB 391
#define PACK_NB 512
#define CAST_NB 6250
__global__ __launch_bounds__(256) void mega_kernel(
    const int* __restrict__ edges,
    int* __restrict__ bcur, unsigned int* __restrict__ packed,
    const float* __restrict__ x,
    const float* __restrict__ W1l, const float* __restrict__ W1r,
    const float* __restrict__ W2l, const float* __restrict__ W2r,
    unsigned short* __restrict__ x_bf,
    unsigned short* __restrict__ B1, unsigned short* __restrict__ B2) {
    __shared__ int hist[NBK];
    __shared__ int scn[NBK];
    __shared__ int gbase[NBK];
    __shared__ int lcur[NBK];
    __shared__ int ps[256];
    __shared__ unsigned int sortbuf[2048];
    __shared__ int gaddrbuf[2048];
    __shared__ int nz;
    int b = blockIdx.x;
    int t = threadIdx.x;
    if (b < FILL_NB) {
        const int E = NE;
        if (t == 0) nz = 0;
        hist[t] = 0; hist[t + 256] = 0;
        __syncthreads();
        int accv = 0;
        for (int i = t; i < 512; i += 256) accv |= edges[2 * i + 1];
        if (accv) atomicOr(&nz, 1);
        __syncthreads();
        int f = nz ? 0 : 1;   // 1 => int64 storage

        int blockbase = b * 2048;
        int nedge = E - blockbase; if (nedge > 2048) nedge = 2048;
        unsigned int pk[8]; int bk[8];
#pragma unroll
        for (int u = 0; u < 8; ++u) {
            int lin = u * 256 + t;
            bk[u] = -1;
            if (lin < nedge) {
                int e = blockbase + lin;
                int src = edges[(size_t)e << f];
                int dst = edges[(size_t)(E + e) << f];
                int bb = dst / NPB;
                pk[u] = (unsigned int)src | ((unsigned int)(dst - bb * NPB) << 16);
                bk[u] = bb;
                atomicAdd(&hist[bb], 1);
            }
        }
        __syncthreads();
        int h0 = hist[2 * t], h1 = hist[2 * t + 1];
        int s = h0 + h1;
        ps[t] = s;
        __syncthreads();
        for (int off = 1; off < 256; off <<= 1) {
            int v = (t >= off) ? ps[t - off] : 0;
            __syncthreads();
            ps[t] += v;
            __syncthreads();
        }
        int excl = ps[t] - s;
        scn[2 * t] = excl;
        scn[2 * t + 1] = excl + h0;
        if (h0) gbase[2 * t] = atomicAdd(&bcur[2 * t], h0);
        if (h1) gbase[2 * t + 1] = atomicAdd(&bcur[2 * t + 1], h1);
        lcur[2 * t] = excl;
        lcur[2 * t + 1] = excl + h0;
        __syncthreads();
#pragma unroll
        for (int u = 0; u < 8; ++u) {
            if (bk[u] >= 0) {
                int p = atomicAdd(&lcur[bk[u]], 1);
                sortbuf[p] = pk[u];
                int off = gbase[bk[u]] + (p - scn[bk[u]]);
                gaddrbuf[p] = (off < BUCKCAP) ? (bk[u] * BUCKCAP + off) : -1;
            }
        }
        __syncthreads();
        for (int j = t; j < nedge; j += 256) {
            int a = gaddrbuf[j];
            if (a >= 0) packed[a] = sortbuf[j];
        }
    } else if (b < FILL_NB + PACK_NB) {
        int idx = (b - FILL_NB) * 256 + t;
        if (idx < 65536) {
            int o = idx >> 8, k = idx & 255;
            float v = (k < 128) ? W1l[o * 128 + k] : W1r[o * 128 + (k - 128)];
            B1[idx] = f2bf(v);
        } else {
            int j = idx - 65536;
            int o = j >> 8, k = j & 255;
            float v = (o < 128) ? W2l[o * 256 + k] : W2r[(o - 128) * 256 + k];
            B2[j] = f2bf(v);
        }
    } else {
        int i4 = (b - FILL_NB - PACK_NB) * 256 + t;
        float4 v = *(const float4*)(x + (size_t)i4 * 4);
        uint2 p;
        p.x = (unsigned int)f2bf(v.x) | ((unsigned int)f2bf(v.y) << 16);
        p.y = (unsigned int)f2bf(v.z) | ((unsigned int)f2bf(v.w) << 16);
        *(uint2*)(x_bf + (size_t)i4 * 4) = p;
    }
}

// ---------------- pass2: per-bucket counting sort -> per-node neighbor lists ----------------
__global__ __launch_bounds__(256) void pass2_kernel(
    const unsigned int* __restrict__ packed, const int* __restrict__ bcur,
    int* __restrict__ nbr, int* __restrict__ row_start, int* __restrict__ deg) {
    __shared__ int hist[NPB];
    __shared__ int scn[NPB];
    __shared__ int lcur[NPB];
    int b = blockIdx.x;
    int t = threadIdx.x;
    int ne = bcur[b]; if (ne > BUCKCAP) ne = BUCKCAP;
    if (t < NPB) hist[t] = 0;
    __syncthreads();
    const unsigned int* pb = packed + (size_t)b * BUCKCAP;
    for (int j = t; j < ne; j += 256) atomicAdd(&hist[pb[j] >> 16], 1);
    __syncthreads();
    if (t == 0) {
        int a = 0;
        for (int i = 0; i < NPB; ++i) { scn[i] = a; a += hist[i]; }
    }
    __syncthreads();
    if (t < NPB) lcur[t] = scn[t];
    __syncthreads();
    for (int j = t; j < ne; j += 256) {
        unsigned int w = pb[j];
        int p = atomicAdd(&lcur[w >> 16], 1);
        nbr[(size_t)b * BUCKCAP + p] = (int)(w & 0xffffu);
    }
    if (t < NPB) {
        int node = b * NPB + t;
        if (node < NN) {
            row_start[node] = b * BUCKCAP + scn[t];
            deg[node] = hist[t];
        }
    }
}

// ---------------- agg1: mean1 = mean_agg(x_bf), width-128 bf16 rows ----------------
__global__ __launch_bounds__(256) void agg1_kernel(
    const unsigned short* __restrict__ X, const int* __restrict__ row_start,
    const int* __restrict__ deg, const int* __restrict__ nbr,
    unsigned short* __restrict__ mean) {
    int node = blockIdx.x * 16 + (threadIdx.x >> 4);
    int l = threadIdx.x & 15;
    if (node >= NN) return;
    int dg = deg[node];
    const int* sl = nbr + row_start[node];
    float a0 = 0.f, a1 = 0.f, a2 = 0.f, a3 = 0.f, a4 = 0.f, a5 = 0.f, a6 = 0.f, a7 = 0.f;
    int i = 0;
    for (; i + 8 <= dg; i += 8) {
        uint4 v[8];
#pragma unroll
        for (int u = 0; u < 8; ++u) {
            int s = sl[i + u];
            v[u] = *(const uint4*)(X + ((size_t)s << 7) + l * 8);
        }
#pragma unroll
        for (int u = 0; u < 8; ++u) {
            a0 += bf_lo(v[u].x); a1 += bf_hi(v[u].x);
            a2 += bf_lo(v[u].y); a3 += bf_hi(v[u].y);
            a4 += bf_lo(v[u].z); a5 += bf_hi(v[u].z);
            a6 += bf_lo(v[u].w); a7 += bf_hi(v[u].w);
        }
    }
    for (; i < dg; ++i) {
        int s = sl[i];
        uint4 v = *(const uint4*)(X + ((size_t)s << 7) + l * 8);
        a0 += bf_lo(v.x); a1 += bf_hi(v.x);
        a2 += bf_lo(v.y); a3 += bf_hi(v.y);
        a4 += bf_lo(v.z); a5 += bf_hi(v.z);
        a6 += bf_lo(v.w); a7 += bf_hi(v.w);
    }
    float inv = 1.0f / (float)(dg > 1 ? dg : 1);
    uint4 p;
    p.x = (unsigned int)f2bf(a0 * inv) | ((unsigned int)f2bf(a1 * inv) << 16);
    p.y = (unsigned int)f2bf(a2 * inv) | ((unsigned int)f2bf(a3 * inv) << 16);
    p.z = (unsigned int)f2bf(a4 * inv) | ((unsigned int)f2bf(a5 * inv) << 16);
    p.w = (unsigned int)f2bf(a6 * inv) | ((unsigned int)f2bf(a7 * inv) << 16);
    *(uint4*)(mean + ((size_t)node << 7) + l * 8) = p;
}

// ---------------- bf16 MFMA GEMM: 64 rows x 256 cols per block ----------------
// A = [A1 | A2] halves along K (ks<2 -> A1, else A2), row strides astr1/astr2.
// LDS: unpadded rows of 8 x 16B granules; slot s of row r holds global granule
// s ^ (r&7) (XOR swizzle, applied on the global gather side so global stays
// line-coalesced). Staged via global_load_lds (DMA, no VGPR round-trip).
// Fragment ds_reads land <=2-way. cols<split -> bf16 out (opt relu), else f32.
__global__ __launch_bounds__(256) void gemm_mfma(
    const unsigned short* __restrict__ A1, const unsigned short* __restrict__ A2,
    int astr1, int astr2,
    const unsigned short* __restrict__ B,
    const float* __restrict__ biasBF, const float* __restrict__ biasF,
    unsigned short* __restrict__ outBF, float* __restrict__ outF,
    int N, int split, int reluBF) {
    __shared__ unsigned short As[64 * 64];    //  8 KB: 64 rows x 8 slots x 8 bf16
    __shared__ unsigned short Bs[256 * 64];   // 32 KB
    int tid = threadIdx.x;
    int row0 = blockIdx.x * 64;
    int w = tid >> 6, lane = tid & 63;
    int q = lane >> 4, l16 = lane & 15;
    int rc = lane >> 3;                 // row within 8-row chunk
    int gsw = (lane & 7) ^ (rc & 7);    // swizzled granule to fetch

    f32x4 acc[4][4];
#pragma unroll
    for (int r = 0; r < 4; ++r)
#pragma unroll
        for (int c = 0; c < 4; ++c) acc[r][c] = (f32x4){0.f, 0.f, 0.f, 0.f};

    for (int ks = 0; ks < 4; ++ks) {
        int kbase = ks * 64;
        if (ks) __syncthreads();   // LDS reuse guard
        const unsigned short* Ap = (ks < 2) ? A1 : A2;
        int astr = (ks < 2) ? astr1 : astr2;
        int koff = (ks & 1) * 64;
        // A: 8 chunks of 8 rows; wave w stages chunks 2w, 2w+1
#pragma unroll
        for (int cc = 0; cc < 2; ++cc) {
            int c = w * 2 + cc;
            int grow = row0 + c * 8 + rc;
            if (grow > N - 1) grow = N - 1;   // clamp: garbage only pollutes unstored rows
            gl_lds16(Ap + (size_t)grow * astr + koff + gsw * 8, &As[c * 512]);
        }
        // B: 32 chunks of 8 rows; wave w stages chunks 8w..8w+7
#pragma unroll
        for (int cc = 0; cc < 8; ++cc) {
            int c = w * 8 + cc;
            int n = c * 8 + rc;
            gl_lds16(B + ((size_t)n << 8) + kbase + gsw * 8, &Bs[c * 512]);
        }
        __syncthreads();   // compiler drains vmcnt before barrier -> data ready
#pragma unroll
        for (int k0 = 0; k0 < 64; k0 += 32) {
            int gb = (k0 >> 3) + q;          // granule index 0..7 within slice
            int sl = gb ^ (l16 & 7);         // swizzled slot
            bf16x8 bfrag[4], afrag[4];
#pragma unroll
            for (int c = 0; c < 4; ++c) {
                int row = w * 64 + c * 16 + l16;
                bfrag[c] = *(const bf16x8*)&Bs[row * 64 + sl * 8];
            }
#pragma unroll
            for (int r = 0; r < 4; ++r) {
                int row = r * 16 + l16;
                afrag[r] = *(const bf16x8*)&As[row * 64 + sl * 8];
            }
#pragma unroll
            for (int r = 0; r < 4; ++r)
#pragma unroll
                for (int c = 0; c < 4; ++c)
                    acc[r][c] = __builtin_amdgcn_mfma_f32_16x16x32_bf16(afrag[r], bfrag[c], acc[r][c], 0, 0, 0);
        }
    }

    // epilogue: D col = lane&15, row = q*4 + reg
#pragma unroll
    for (int c = 0; c < 4; ++c) {
        int colg = w * 64 + c * 16 + l16;
        bool isBF = (colg < split);
        float bb = 0.f;
        if (isBF) { if (biasBF) bb = biasBF[colg]; }
        else      bb = biasF[colg - split];
#pragma unroll
        for (int r = 0; r < 4; ++r) {
#pragma unroll
            for (int reg = 0; reg < 4; ++reg) {
                int rowg = row0 + r * 16 + q * 4 + reg;
                if (rowg < N) {
                    float v = acc[r][c][reg] + bb;
                    if (isBF) {
                        if (reluBF) v = fmaxf(v, 0.f);
                        outBF[(size_t)rowg * split + colg] = f2bf(v);
                    } else {
                        outF[(size_t)rowg * (256 - split) + (colg - split)] = v;
                    }
                }
            }
        }
    }
}

// ---------------- agg2: out = mean_agg(P) + R ----------------
__global__ __launch_bounds__(256) void agg2_kernel(
    const unsigned short* __restrict__ P, const float* __restrict__ R,
    const int* __restrict__ row_start, const int* __restrict__ deg,
    const int* __restrict__ nbr, float* __restrict__ out) {
    int node = blockIdx.x * 16 + (threadIdx.x >> 4);
    int l = threadIdx.x & 15;
    if (node >= NN) return;
    int dg = deg[node];
    const int* sl = nbr + row_start[node];
    float a0 = 0.f, a1 = 0.f, a2 = 0.f, a3 = 0.f, a4 = 0.f, a5 = 0.f, a6 = 0.f, a7 = 0.f;
    int i = 0;
    for (; i + 8 <= dg; i += 8) {
        uint4 v[8];
#pragma unroll
        for (int u = 0; u < 8; ++u) {
            int s = sl[i + u];
            v[u] = *(const uint4*)(P + ((size_t)s << 7) + l * 8);
        }
#pragma unroll
        for (int u = 0; u < 8; ++u) {
            a0 += bf_lo(v[u].x); a1 += bf_hi(v[u].x);
            a2 += bf_lo(v[u].y); a3 += bf_hi(v[u].y);
            a4 += bf_lo(v[u].z); a5 += bf_hi(v[u].z);
            a6 += bf_lo(v[u].w); a7 += bf_hi(v[u].w);
        }
    }
    for (; i < dg; ++i) {
        int s = sl[i];
        uint4 v = *(const uint4*)(P + ((size_t)s << 7) + l * 8);
        a0 += bf_lo(v.x); a1 += bf_hi(v.x);
        a2 += bf_lo(v.y); a3 += bf_hi(v.y);
        a4 += bf_lo(v.z); a5 += bf_hi(v.z);
        a6 += bf_lo(v.w); a7 += bf_hi(v.w);
    }
    float inv = 1.0f / (float)(dg > 1 ? dg : 1);
    const float* rrow = R + ((size_t)node << 7) + l * 8;
    float4 r0 = *(const float4*)rrow;
    float4 r1 = *(const float4*)(rrow + 4);
    float4 o0, o1;
    o0.x = a0 * inv + r0.x; o0.y = a1 * inv + r0.y;
    o0.z = a2 * inv + r0.z; o0.w = a3 * inv + r0.w;
    o1.x = a4 * inv + r1.x; o1.y = a5 * inv + r1.y;
    o1.z = a6 * inv + r1.z; o1.w = a7 * inv + r1.w;
    float* orow = out + ((size_t)node << 7) + l * 8;
    *(float4*)orow = o0;
    *(float4*)(orow + 4) = o1;
}

extern "C" void kernel_launch(void* const* d_in, const int* in_sizes, int n_in,
                              void* d_out, int out_size, void* d_ws, size_t ws_size,
                              hipStream_t stream) {
    const float* x    = (const float*)d_in[0];
    const int*   edges = (const int*)d_in[1];
    const float* W1_l = (const float*)d_in[2];
    const float* b1   = (const float*)d_in[3];
    const float* W1_r = (const float*)d_in[4];
    const float* W2_l = (const float*)d_in[5];
    const float* b2   = (const float*)d_in[6];
    const float* W2_r = (const float*)d_in[7];
    float* out = (float*)d_out;

    const int N = NN;
    auto al = [](size_t v) { return (v + 255) & ~(size_t)255; };
    char* ws = (char*)d_ws;
    size_t o = 0;
    int* bcur = (int*)(ws + o); o += al((size_t)NBK * 4);
    unsigned int* packed = (unsigned int*)(ws + o); o += al((size_t)NBK * BUCKCAP * 4);
    int* nbr       = (int*)(ws + o); o += al((size_t)NBK * BUCKCAP * 4);
    int* row_start = (int*)(ws + o); o += al((size_t)N * 4);
    int* deg       = (int*)(ws + o); o += al((size_t)N * 4);
    unsigned short* x_bf  = (unsigned short*)(ws + o); o += al((size_t)N * 128 * 2);
    unsigned short* mean1 = (unsigned short*)(ws + o); o += al((size_t)N * 128 * 2);
    unsigned short* h_bf  = (unsigned short*)(ws + o); o += al((size_t)N * 256 * 2);
    unsigned short* P_bf  = (unsigned short*)(ws + o); o += al((size_t)N * 128 * 2);
    float*          R_f   = (float*)(ws + o);          o += al((size_t)N * 128 * 4);
    unsigned short* B1    = (unsigned short*)(ws + o); o += al((size_t)256 * 256 * 2);
    unsigned short* B2    = (unsigned short*)(ws + o); o += al((size_t)256 * 256 * 2);

    // 1) zero bucket cursors (2 KB)
    hipMemsetAsync(bcur, 0, (size_t)NBK * 4, stream);
    // 2) bin-scatter + packB + cast_x in one dispatch
    mega_kernel<<<FILL_NB + PACK_NB + CAST_NB, 256, 0, stream>>>(
        edges, bcur, packed, x, W1_l, W1_r, W2_l, W2_r, x_bf, B1, B2);
    // 3) per-bucket counting sort -> nbr / row_start / deg
    pass2_kernel<<<NBK, 256, 0, stream>>>(packed, bcur, nbr, row_start, deg);
    // 4) mean1 = mean_agg(x_bf)
    agg1_kernel<<<(N + 15) / 16, 256, 0, stream>>>(x_bf, row_start, deg, nbr, mean1);
    // 5) h = relu([mean1||x_bf] @ B1^T + b1)  (bf16)
    gemm_mfma<<<(N + 63) / 64, 256, 0, stream>>>(mean1, x_bf, 128, 128, B1, b1, b1,
                                                 h_bf, (float*)nullptr, N, 256, 1);
    // 6) [P||R] = h @ B2^T ; P bf16 (no bias), R f32 (+b2)
    gemm_mfma<<<(N + 63) / 64, 256, 0, stream>>>(h_bf, h_bf + 128, 256, 256, B2,
                                                 (float*)nullptr, b2, P_bf, R_f, N, 128, 0);
    // 7) out = mean_agg(P) + R
    agg2_kernel<<<(N + 15) / 16, 256, 0, stream>>>(P_bf, R_f, row_start, deg, nbr, out);
}

// Round 10
// 243.625 us; speedup vs baseline: 1.3884x; 1.0325x over previous
//
#include <hip/hip_runtime.h>
#include <stdint.h>

#define NN 50000
#define NE 800000
#define NBK 512          // dst buckets
#define NPB 98           // nodes per bucket (512*98 = 50176 >= 50000)
#define BUCKCAP 2048     // edges per bucket region; mean 1568 -> 12 sigma margin
// layer1: in=128 hid=256; layer2: in=256 out=128
// Layer-2 restructured: out = mean_agg(h @ W2_l^T) + (h @ W2_r^T + b2)
// R5: never fuse gather phase into MFMA kernel. R7: scatter atomics op-count-bound.
// R8: m97-style global_load_lds GEMM staging. R9: no dominant kernel left;
//   consolidate dispatches -> pass2+agg1 fused (lists live in LDS), ushort nbr.

typedef __bf16 bf16x8 __attribute__((ext_vector_type(8)));
typedef float  f32x4  __attribute__((ext_vector_type(4)));

__device__ __forceinline__ unsigned short f2bf(float f) {
    unsigned int u = __float_as_uint(f);
    unsigned int r = (u + 0x7fffu + ((u >> 16) & 1u)) >> 16;   // RNE
    return (unsigned short)r;
}
__device__ __forceinline__ float bf_lo(unsigned int v) { return __uint_as_float(v << 16); }
__device__ __forceinline__ float bf_hi(unsigned int v) { return __uint_as_float(v & 0xffff0000u); }

// async global->LDS, 16 B per lane; lds base wave-uniform, lane i lands at base+16i
__device__ __forceinline__ void gl_lds16(const void* g, void* l) {
    __builtin_amdgcn_global_load_lds(
        (const __attribute__((address_space(1))) void*)g,
        (__attribute__((address_space(3))) void*)l, 16, 0, 0);
}

// ---------------- prep: zero bcur + pack B1/B2 ----------------
// block 0: zero bcur; blocks 1..512: pack 131072 weight elems.
__global__ __launch_bounds__(256) void prep_kernel(
    int* __restrict__ bcur,
    const float* __restrict__ W1l, const float* __restrict__ W1r,
    const float* __restrict__ W2l, const float* __restrict__ W2r,
    unsigned short* __restrict__ B1, unsigned short* __restrict__ B2) {
    int b = blockIdx.x, t = threadIdx.x;
    if (b == 0) {
        bcur[t] = 0; bcur[t + 256] = 0;
    } else {
        int idx = (b - 1) * 256 + t;   // 0..131071
        if (idx < 65536) {
            int o = idx >> 8, k = idx & 255;
            float v = (k < 128) ? W1l[o * 128 + k] : W1r[o * 128 + (k - 128)];
            B1[idx] = f2bf(v);
        } else {
            int j = idx - 65536;
            int o = j >> 8, k = j & 255;
            float v = (o < 128) ? W2l[o * 256 + k] : W2r[(o - 128) * 256 + k];
            B2[j] = f2bf(v);
        }
    }
}

// ---------------- mega: bucket bin-scatter + cast_x in one dispatch ----------------
#define FILL_NB 391
#define CAST_NB 6250
__global__ __launch_bounds__(256) void mega_kernel(
    const int* __restrict__ edges,
    int* __restrict__ bcur, unsigned int* __restrict__ packed,
    const float* __restrict__ x, unsigned short* __restrict__ x_bf) {
    __shared__ int hist[NBK];
    __shared__ int scn[NBK];
    __shared__ int gbase[NBK];
    __shared__ int lcur[NBK];
    __shared__ int ps[256];
    __shared__ unsigned int sortbuf[2048];
    __shared__ int gaddrbuf[2048];
    __shared__ int nz;
    int b = blockIdx.x;
    int t = threadIdx.x;
    if (b < FILL_NB) {
        const int E = NE;
        // edge dtype detect: odd words of first 512 pairs all zero <=> int64 storage
        if (t == 0) nz = 0;
        hist[t] = 0; hist[t + 256] = 0;
        __syncthreads();
        int accv = 0;
        for (int i = t; i < 512; i += 256) accv |= edges[2 * i + 1];
        if (accv) atomicOr(&nz, 1);
        __syncthreads();
        int f = nz ? 0 : 1;   // 1 => int64 storage

        int blockbase = b * 2048;
        int nedge = E - blockbase; if (nedge > 2048) nedge = 2048;
        unsigned int pk[8]; int bk[8];
#pragma unroll
        for (int u = 0; u < 8; ++u) {
            int lin = u * 256 + t;
            bk[u] = -1;
            if (lin < nedge) {
                int e = blockbase + lin;
                int src = edges[(size_t)e << f];
                int dst = edges[(size_t)(E + e) << f];
                int bb = dst / NPB;
                pk[u] = (unsigned int)src | ((unsigned int)(dst - bb * NPB) << 16);
                bk[u] = bb;
                atomicAdd(&hist[bb], 1);
            }
        }
        __syncthreads();
        int h0 = hist[2 * t], h1 = hist[2 * t + 1];
        int s = h0 + h1;
        ps[t] = s;
        __syncthreads();
        for (int off = 1; off < 256; off <<= 1) {
            int v = (t >= off) ? ps[t - off] : 0;
            __syncthreads();
            ps[t] += v;
            __syncthreads();
        }
        int excl = ps[t] - s;
        scn[2 * t] = excl;
        scn[2 * t + 1] = excl + h0;
        if (h0) gbase[2 * t] = atomicAdd(&bcur[2 * t], h0);
        if (h1) gbase[2 * t + 1] = atomicAdd(&bcur[2 * t + 1], h1);
        lcur[2 * t] = excl;
        lcur[2 * t + 1] = excl + h0;
        __syncthreads();
#pragma unroll
        for (int u = 0; u < 8; ++u) {
            if (bk[u] >= 0) {
                int p = atomicAdd(&lcur[bk[u]], 1);
                sortbuf[p] = pk[u];
                int off = gbase[bk[u]] + (p - scn[bk[u]]);
                gaddrbuf[p] = (off < BUCKCAP) ? (bk[u] * BUCKCAP + off) : -1;
            }
        }
        __syncthreads();
        for (int j = t; j < nedge; j += 256) {
            int a = gaddrbuf[j];
            if (a >= 0) packed[a] = sortbuf[j];
        }
    } else {
        int i4 = (b - FILL_NB) * 256 + t;   // one float4 each
        float4 v = *(const float4*)(x + (size_t)i4 * 4);
        uint2 p;
        p.x = (unsigned int)f2bf(v.x) | ((unsigned int)f2bf(v.y) << 16);
        p.y = (unsigned int)f2bf(v.z) | ((unsigned int)f2bf(v.w) << 16);
        *(uint2*)(x_bf + (size_t)i4 * 4) = p;
    }
}

// ---------------- pass2+agg1 fused: per-bucket counting sort -> LDS lists -> mean1 ----------
// One 512-thread block per bucket. Lists stay in LDS (ushort src); CSR (ushort nbr,
// row_start, deg) written for agg2; mean1 aggregated immediately from the LDS lists.
__global__ __launch_bounds__(512) void pass2agg1_kernel(
    const unsigned int* __restrict__ packed, const int* __restrict__ bcur,
    const unsigned short* __restrict__ X,
    unsigned short* __restrict__ nbr, int* __restrict__ row_start, int* __restrict__ deg,
    unsigned short* __restrict__ mean) {
    __shared__ int hist[NPB];
    __shared__ int scn[NPB];
    __shared__ int lcur[NPB];
    __shared__ unsigned short lists[BUCKCAP];
    int b = blockIdx.x;
    int t = threadIdx.x;
    int ne = bcur[b]; if (ne > BUCKCAP) ne = BUCKCAP;
    if (t < NPB) hist[t] = 0;
    __syncthreads();
    const unsigned int* pb = packed + (size_t)b * BUCKCAP;
    for (int j = t; j < ne; j += 512) atomicAdd(&hist[pb[j] >> 16], 1);
    __syncthreads();
    if (t == 0) {
        int a = 0;
        for (int i = 0; i < NPB; ++i) { scn[i] = a; a += hist[i]; }
    }
    __syncthreads();
    if (t < NPB) lcur[t] = scn[t];
    __syncthreads();
    for (int j = t; j < ne; j += 512) {
        unsigned int w = pb[j];
        int p = atomicAdd(&lcur[w >> 16], 1);
        lists[p] = (unsigned short)(w & 0xffffu);   // src < 50000 < 65536
    }
    __syncthreads();
    // CSR out for agg2
    if (t < NPB) {
        int node = b * NPB + t;
        if (node < NN) {
            row_start[node] = b * BUCKCAP + scn[t];
            deg[node] = hist[t];
        }
    }
    for (int j = t; j < ne; j += 512) nbr[(size_t)b * BUCKCAP + j] = lists[j];
    // aggregate this bucket's nodes: quarter-wave (16 lanes) per node, 8x unroll
    int qw = t >> 4;      // 0..31
    int l = t & 15;
    for (int n = qw; n < NPB; n += 32) {
        int node = b * NPB + n;
        if (node >= NN) break;
        int dg = hist[n];
        const unsigned short* sl = &lists[scn[n]];
        float a0 = 0.f, a1 = 0.f, a2 = 0.f, a3 = 0.f, a4 = 0.f, a5 = 0.f, a6 = 0.f, a7 = 0.f;
        int i = 0;
        for (; i + 8 <= dg; i += 8) {
            uint4 v[8];
#pragma unroll
            for (int u = 0; u < 8; ++u) {
                int s = sl[i + u];
                v[u] = *(const uint4*)(X + ((size_t)s << 7) + l * 8);
            }
#pragma unroll
            for (int u = 0; u < 8; ++u) {
                a0 += bf_lo(v[u].x); a1 += bf_hi(v[u].x);
                a2 += bf_lo(v[u].y); a3 += bf_hi(v[u].y);
                a4 += bf_lo(v[u].z); a5 += bf_hi(v[u].z);
                a6 += bf_lo(v[u].w); a7 += bf_hi(v[u].w);
            }
        }
        for (; i < dg; ++i) {
            int s = sl[i];
            uint4 v = *(const uint4*)(X + ((size_t)s << 7) + l * 8);
            a0 += bf_lo(v.x); a1 += bf_hi(v.x);
            a2 += bf_lo(v.y); a3 += bf_hi(v.y);
            a4 += bf_lo(v.z); a5 += bf_hi(v.z);
            a6 += bf_lo(v.w); a7 += bf_hi(v.w);
        }
        float inv = 1.0f / (float)(dg > 1 ? dg : 1);
        uint4 p;
        p.x = (unsigned int)f2bf(a0 * inv) | ((unsigned int)f2bf(a1 * inv) << 16);
        p.y = (unsigned int)f2bf(a2 * inv) | ((unsigned int)f2bf(a3 * inv) << 16);
        p.z = (unsigned int)f2bf(a4 * inv) | ((unsigned int)f2bf(a5 * inv) << 16);
        p.w = (unsigned int)f2bf(a6 * inv) | ((unsigned int)f2bf(a7 * inv) << 16);
        *(uint4*)(mean + ((size_t)node << 7) + l * 8) = p;
    }
}

// ---------------- bf16 MFMA GEMM: 64 rows x 256 cols per block (R9 m97-style) ----------------
__global__ __launch_bounds__(256) void gemm_mfma(
    const unsigned short* __restrict__ A1, const unsigned short* __restrict__ A2,
    int astr1, int astr2,
    const unsigned short* __restrict__ B,
    const float* __restrict__ biasBF, const float* __restrict__ biasF,
    unsigned short* __restrict__ outBF, float* __restrict__ outF,
    int N, int split, int reluBF) {
    __shared__ unsigned short As[64 * 64];    //  8 KB: 64 rows x 8 slots x 8 bf16
    __shared__ unsigned short Bs[256 * 64];   // 32 KB
    int tid = threadIdx.x;
    int row0 = blockIdx.x * 64;
    int w = tid >> 6, lane = tid & 63;
    int q = lane >> 4, l16 = lane & 15;
    int rc = lane >> 3;                 // row within 8-row chunk
    int gsw = (lane & 7) ^ (rc & 7);    // swizzled granule to fetch

    f32x4 acc[4][4];
#pragma unroll
    for (int r = 0; r < 4; ++r)
#pragma unroll
        for (int c = 0; c < 4; ++c) acc[r][c] = (f32x4){0.f, 0.f, 0.f, 0.f};

    for (int ks = 0; ks < 4; ++ks) {
        int kbase = ks * 64;
        if (ks) __syncthreads();
        const unsigned short* Ap = (ks < 2) ? A1 : A2;
        int astr = (ks < 2) ? astr1 : astr2;
        int koff = (ks & 1) * 64;
#pragma unroll
        for (int cc = 0; cc < 2; ++cc) {
            int c = w * 2 + cc;
            int grow = row0 + c * 8 + rc;
            if (grow > N - 1) grow = N - 1;
            gl_lds16(Ap + (size_t)grow * astr + koff + gsw * 8, &As[c * 512]);
        }
#pragma unroll
        for (int cc = 0; cc < 8; ++cc) {
            int c = w * 8 + cc;
            int n = c * 8 + rc;
            gl_lds16(B + ((size_t)n << 8) + kbase + gsw * 8, &Bs[c * 512]);
        }
        __syncthreads();
#pragma unroll
        for (int k0 = 0; k0 < 64; k0 += 32) {
            int gb = (k0 >> 3) + q;
            int sl = gb ^ (l16 & 7);
            bf16x8 bfrag[4], afrag[4];
#pragma unroll
            for (int c = 0; c < 4; ++c) {
                int row = w * 64 + c * 16 + l16;
                bfrag[c] = *(const bf16x8*)&Bs[row * 64 + sl * 8];
            }
#pragma unroll
            for (int r = 0; r < 4; ++r) {
                int row = r * 16 + l16;
                afrag[r] = *(const bf16x8*)&As[row * 64 + sl * 8];
            }
#pragma unroll
            for (int r = 0; r < 4; ++r)
#pragma unroll
                for (int c = 0; c < 4; ++c)
                    acc[r][c] = __builtin_amdgcn_mfma_f32_16x16x32_bf16(afrag[r], bfrag[c], acc[r][c], 0, 0, 0);
        }
    }

#pragma unroll
    for (int c = 0; c < 4; ++c) {
        int colg = w * 64 + c * 16 + l16;
        bool isBF = (colg < split);
        float bb = 0.f;
        if (isBF) { if (biasBF) bb = biasBF[colg]; }
        else      bb = biasF[colg - split];
#pragma unroll
        for (int r = 0; r < 4; ++r) {
#pragma unroll
            for (int reg = 0; reg < 4; ++reg) {
                int rowg = row0 + r * 16 + q * 4 + reg;
                if (rowg < N) {
                    float v = acc[r][c][reg] + bb;
                    if (isBF) {
                        if (reluBF) v = fmaxf(v, 0.f);
                        outBF[(size_t)rowg * split + colg] = f2bf(v);
                    } else {
                        outF[(size_t)rowg * (256 - split) + (colg - split)] = v;
                    }
                }
            }
        }
    }
}

// ---------------- agg2: out = mean_agg(P) + R (ushort nbr) ----------------
__global__ __launch_bounds__(256) void agg2_kernel(
    const unsigned short* __restrict__ P, const float* __restrict__ R,
    const int* __restrict__ row_start, const int* __restrict__ deg,
    const unsigned short* __restrict__ nbr, float* __restrict__ out) {
    int node = blockIdx.x * 16 + (threadIdx.x >> 4);
    int l = threadIdx.x & 15;
    if (node >= NN) return;
    int dg = deg[node];
    const unsigned short* sl = nbr + row_start[node];
    float a0 = 0.f, a1 = 0.f, a2 = 0.f, a3 = 0.f, a4 = 0.f, a5 = 0.f, a6 = 0.f, a7 = 0.f;
    int i = 0;
    for (; i + 8 <= dg; i += 8) {
        uint4 v[8];
#pragma unroll
        for (int u = 0; u < 8; ++u) {
            int s = sl[i + u];
            v[u] = *(const uint4*)(P + ((size_t)s << 7) + l * 8);
        }
#pragma unroll
        for (int u = 0; u < 8; ++u) {
            a0 += bf_lo(v[u].x); a1 += bf_hi(v[u].x);
            a2 += bf_lo(v[u].y); a3 += bf_hi(v[u].y);
            a4 += bf_lo(v[u].z); a5 += bf_hi(v[u].z);
            a6 += bf_lo(v[u].w); a7 += bf_hi(v[u].w);
        }
    }
    for (; i < dg; ++i) {
        int s = sl[i];
        uint4 v = *(const uint4*)(P + ((size_t)s << 7) + l * 8);
        a0 += bf_lo(v.x); a1 += bf_hi(v.x);
        a2 += bf_lo(v.y); a3 += bf_hi(v.y);
        a4 += bf_lo(v.z); a5 += bf_hi(v.z);
        a6 += bf_lo(v.w); a7 += bf_hi(v.w);
    }
    float inv = 1.0f / (float)(dg > 1 ? dg : 1);
    const float* rrow = R + ((size_t)node << 7) + l * 8;
    float4 r0 = *(const float4*)rrow;
    float4 r1 = *(const float4*)(rrow + 4);
    float4 o0, o1;
    o0.x = a0 * inv + r0.x; o0.y = a1 * inv + r0.y;
    o0.z = a2 * inv + r0.z; o0.w = a3 * inv + r0.w;
    o1.x = a4 * inv + r1.x; o1.y = a5 * inv + r1.y;
    o1.z = a6 * inv + r1.z; o1.w = a7 * inv + r1.w;
    float* orow = out + ((size_t)node << 7) + l * 8;
    *(float4*)orow = o0;
    *(float4*)(orow + 4) = o1;
}

extern "C" void kernel_launch(void* const* d_in, const int* in_sizes, int n_in,
                              void* d_out, int out_size, void* d_ws, size_t ws_size,
                              hipStream_t stream) {
    const float* x    = (const float*)d_in[0];
    const int*   edges = (const int*)d_in[1];
    const float* W1_l = (const float*)d_in[2];
    const float* b1   = (const float*)d_in[3];
    const float* W1_r = (const float*)d_in[4];
    const float* W2_l = (const float*)d_in[5];
    const float* b2   = (const float*)d_in[6];
    const float* W2_r = (const float*)d_in[7];
    float* out = (float*)d_out;

    const int N = NN;
    auto al = [](size_t v) { return (v + 255) & ~(size_t)255; };
    char* ws = (char*)d_ws;
    size_t o = 0;
    int* bcur = (int*)(ws + o); o += al((size_t)NBK * 4);
    unsigned int* packed = (unsigned int*)(ws + o); o += al((size_t)NBK * BUCKCAP * 4);
    unsigned short* nbr = (unsigned short*)(ws + o); o += al((size_t)NBK * BUCKCAP * 2);
    int* row_start = (int*)(ws + o); o += al((size_t)N * 4);
    int* deg       = (int*)(ws + o); o += al((size_t)N * 4);
    unsigned short* x_bf  = (unsigned short*)(ws + o); o += al((size_t)N * 128 * 2);
    unsigned short* mean1 = (unsigned short*)(ws + o); o += al((size_t)N * 128 * 2);
    unsigned short* h_bf  = (unsigned short*)(ws + o); o += al((size_t)N * 256 * 2);
    unsigned short* P_bf  = (unsigned short*)(ws + o); o += al((size_t)N * 128 * 2);
    float*          R_f   = (float*)(ws + o);          o += al((size_t)N * 128 * 4);
    unsigned short* B1    = (unsigned short*)(ws + o); o += al((size_t)256 * 256 * 2);
    unsigned short* B2    = (unsigned short*)(ws + o); o += al((size_t)256 * 256 * 2);

    // 1) zero bucket cursors + pack B1/B2
    prep_kernel<<<513, 256, 0, stream>>>(bcur, W1_l, W1_r, W2_l, W2_r, B1, B2);
    // 2) bin-scatter + cast_x in one dispatch
    mega_kernel<<<FILL_NB + CAST_NB, 256, 0, stream>>>(edges, bcur, packed, x, x_bf);
    // 3) per-bucket counting sort + mean1 aggregation (lists in LDS), CSR out for agg2
    pass2agg1_kernel<<<NBK, 512, 0, stream>>>(packed, bcur, x_bf, nbr, row_start, deg, mean1);
    // 4) h = relu([mean1||x_bf] @ B1^T + b1)  (bf16)
    gemm_mfma<<<(N + 63) / 64, 256, 0, stream>>>(mean1, x_bf, 128, 128, B1, b1, b1,
                                                 h_bf, (float*)nullptr, N, 256, 1);
    // 5) [P||R] = h @ B2^T ; P bf16 (no bias), R f32 (+b2)
    gemm_mfma<<<(N + 63) / 64, 256, 0, stream>>>(h_bf, h_bf + 128, 256, 256, B2,
                                                 (float*)nullptr, b2, P_bf, R_f, N, 128, 0);
    // 6) out = mean_agg(P) + R
    agg2_kernel<<<(N + 15) / 16, 256, 0, stream>>>(P_bf, R_f, row_start, deg, nbr, out);
}

// Round 11
// 218.328 us; speedup vs baseline: 1.5492x; 1.1159x over previous
//
#include <hip/hip_runtime.h>
#include <stdint.h>

#define NN 50000
#define NE 800000
#define NBK 512          // dst buckets
#define NPB 98           // nodes per bucket (512*98 = 50176 >= 50000)
#define BUCKCAP 2048     // edges per bucket region; mean 1568 -> 12 sigma margin
// layer1: in=128 hid=256; layer2: in=256 out=128
// Layer-2 restructured: out = mean_agg(h @ W2_l^T) + (h @ W2_r^T + b2)
// R5: never fuse gather phase into MFMA kernel. R7: scatter atomics op-count-bound.
// R8: m97-style global_load_lds staging + XOR swizzle (R10: conflicts -> 0).
// R10 lesson: 64-row tile re-stages full B per block (100 MB L2) and does too few
//   MFMAs per barrier drain -> 128x256 tile, 8 waves, B re-staging halved.

typedef __bf16 bf16x8 __attribute__((ext_vector_type(8)));
typedef float  f32x4  __attribute__((ext_vector_type(4)));

__device__ __forceinline__ unsigned short f2bf(float f) {
    unsigned int u = __float_as_uint(f);
    unsigned int r = (u + 0x7fffu + ((u >> 16) & 1u)) >> 16;   // RNE
    return (unsigned short)r;
}
__device__ __forceinline__ float bf_lo(unsigned int v) { return __uint_as_float(v << 16); }
__device__ __forceinline__ float bf_hi(unsigned int v) { return __uint_as_float(v & 0xffff0000u); }

// async global->LDS, 16 B per lane; lds base wave-uniform, lane i lands at base+16i
__device__ __forceinline__ void gl_lds16(const void* g, void* l) {
    __builtin_amdgcn_global_load_lds(
        (const __attribute__((address_space(1))) void*)g,
        (__attribute__((address_space(3))) void*)l, 16, 0, 0);
}

// ---------------- prep: zero bcur + pack B1/B2 ----------------
__global__ __launch_bounds__(256) void prep_kernel(
    int* __restrict__ bcur,
    const float* __restrict__ W1l, const float* __restrict__ W1r,
    const float* __restrict__ W2l, const float* __restrict__ W2r,
    unsigned short* __restrict__ B1, unsigned short* __restrict__ B2) {
    int b = blockIdx.x, t = threadIdx.x;
    if (b == 0) {
        bcur[t] = 0; bcur[t + 256] = 0;
    } else {
        int idx = (b - 1) * 256 + t;   // 0..131071
        if (idx < 65536) {
            int o = idx >> 8, k = idx & 255;
            float v = (k < 128) ? W1l[o * 128 + k] : W1r[o * 128 + (k - 128)];
            B1[idx] = f2bf(v);
        } else {
            int j = idx - 65536;
            int o = j >> 8, k = j & 255;
            float v = (o < 128) ? W2l[o * 256 + k] : W2r[(o - 128) * 256 + k];
            B2[j] = f2bf(v);
        }
    }
}

// ---------------- mega: bucket bin-scatter + cast_x in one dispatch ----------------
#define FILL_NB 391
#define CAST_NB 6250
__global__ __launch_bounds__(256) void mega_kernel(
    const int* __restrict__ edges,
    int* __restrict__ bcur, unsigned int* __restrict__ packed,
    const float* __restrict__ x, unsigned short* __restrict__ x_bf) {
    __shared__ int hist[NBK];
    __shared__ int scn[NBK];
    __shared__ int gbase[NBK];
    __shared__ int lcur[NBK];
    __shared__ int ps[256];
    __shared__ unsigned int sortbuf[2048];
    __shared__ int gaddrbuf[2048];
    __shared__ int nz;
    int b = blockIdx.x;
    int t = threadIdx.x;
    if (b < FILL_NB) {
        const int E = NE;
        if (t == 0) nz = 0;
        hist[t] = 0; hist[t + 256] = 0;
        __syncthreads();
        int accv = 0;
        for (int i = t; i < 512; i += 256) accv |= edges[2 * i + 1];
        if (accv) atomicOr(&nz, 1);
        __syncthreads();
        int f = nz ? 0 : 1;   // 1 => int64 storage

        int blockbase = b * 2048;
        int nedge = E - blockbase; if (nedge > 2048) nedge = 2048;
        unsigned int pk[8]; int bk[8];
#pragma unroll
        for (int u = 0; u < 8; ++u) {
            int lin = u * 256 + t;
            bk[u] = -1;
            if (lin < nedge) {
                int e = blockbase + lin;
                int src = edges[(size_t)e << f];
                int dst = edges[(size_t)(E + e) << f];
                int bb = dst / NPB;
                pk[u] = (unsigned int)src | ((unsigned int)(dst - bb * NPB) << 16);
                bk[u] = bb;
                atomicAdd(&hist[bb], 1);
            }
        }
        __syncthreads();
        int h0 = hist[2 * t], h1 = hist[2 * t + 1];
        int s = h0 + h1;
        ps[t] = s;
        __syncthreads();
        for (int off = 1; off < 256; off <<= 1) {
            int v = (t >= off) ? ps[t - off] : 0;
            __syncthreads();
            ps[t] += v;
            __syncthreads();
        }
        int excl = ps[t] - s;
        scn[2 * t] = excl;
        scn[2 * t + 1] = excl + h0;
        if (h0) gbase[2 * t] = atomicAdd(&bcur[2 * t], h0);
        if (h1) gbase[2 * t + 1] = atomicAdd(&bcur[2 * t + 1], h1);
        lcur[2 * t] = excl;
        lcur[2 * t + 1] = excl + h0;
        __syncthreads();
#pragma unroll
        for (int u = 0; u < 8; ++u) {
            if (bk[u] >= 0) {
                int p = atomicAdd(&lcur[bk[u]], 1);
                sortbuf[p] = pk[u];
                int off = gbase[bk[u]] + (p - scn[bk[u]]);
                gaddrbuf[p] = (off < BUCKCAP) ? (bk[u] * BUCKCAP + off) : -1;
            }
        }
        __syncthreads();
        for (int j = t; j < nedge; j += 256) {
            int a = gaddrbuf[j];
            if (a >= 0) packed[a] = sortbuf[j];
        }
    } else {
        int i4 = (b - FILL_NB) * 256 + t;   // one float4 each
        float4 v = *(const float4*)(x + (size_t)i4 * 4);
        uint2 p;
        p.x = (unsigned int)f2bf(v.x) | ((unsigned int)f2bf(v.y) << 16);
        p.y = (unsigned int)f2bf(v.z) | ((unsigned int)f2bf(v.w) << 16);
        *(uint2*)(x_bf + (size_t)i4 * 4) = p;
    }
}

// ---------------- pass2+agg1 fused: per-bucket counting sort -> LDS lists -> mean1 ----------
__global__ __launch_bounds__(512) void pass2agg1_kernel(
    const unsigned int* __restrict__ packed, const int* __restrict__ bcur,
    const unsigned short* __restrict__ X,
    unsigned short* __restrict__ nbr, int* __restrict__ row_start, int* __restrict__ deg,
    unsigned short* __restrict__ mean) {
    __shared__ int hist[NPB];
    __shared__ int scn[NPB];
    __shared__ int lcur[NPB];
    __shared__ unsigned short lists[BUCKCAP];
    int b = blockIdx.x;
    int t = threadIdx.x;
    int ne = bcur[b]; if (ne > BUCKCAP) ne = BUCKCAP;
    if (t < NPB) hist[t] = 0;
    __syncthreads();
    const unsigned int* pb = packed + (size_t)b * BUCKCAP;
    for (int j = t; j < ne; j += 512) atomicAdd(&hist[pb[j] >> 16], 1);
    __syncthreads();
    if (t == 0) {
        int a = 0;
        for (int i = 0; i < NPB; ++i) { scn[i] = a; a += hist[i]; }
    }
    __syncthreads();
    if (t < NPB) lcur[t] = scn[t];
    __syncthreads();
    for (int j = t; j < ne; j += 512) {
        unsigned int w = pb[j];
        int p = atomicAdd(&lcur[w >> 16], 1);
        lists[p] = (unsigned short)(w & 0xffffu);   // src < 50000 < 65536
    }
    __syncthreads();
    if (t < NPB) {
        int node = b * NPB + t;
        if (node < NN) {
            row_start[node] = b * BUCKCAP + scn[t];
            deg[node] = hist[t];
        }
    }
    for (int j = t; j < ne; j += 512) nbr[(size_t)b * BUCKCAP + j] = lists[j];
    int qw = t >> 4;      // 0..31
    int l = t & 15;
    for (int n = qw; n < NPB; n += 32) {
        int node = b * NPB + n;
        if (node >= NN) break;
        int dg = hist[n];
        const unsigned short* sl = &lists[scn[n]];
        float a0 = 0.f, a1 = 0.f, a2 = 0.f, a3 = 0.f, a4 = 0.f, a5 = 0.f, a6 = 0.f, a7 = 0.f;
        int i = 0;
        for (; i + 8 <= dg; i += 8) {
            uint4 v[8];
#pragma unroll
            for (int u = 0; u < 8; ++u) {
                int s = sl[i + u];
                v[u] = *(const uint4*)(X + ((size_t)s << 7) + l * 8);
            }
#pragma unroll
            for (int u = 0; u < 8; ++u) {
                a0 += bf_lo(v[u].x); a1 += bf_hi(v[u].x);
                a2 += bf_lo(v[u].y); a3 += bf_hi(v[u].y);
                a4 += bf_lo(v[u].z); a5 += bf_hi(v[u].z);
                a6 += bf_lo(v[u].w); a7 += bf_hi(v[u].w);
            }
        }
        for (; i < dg; ++i) {
            int s = sl[i];
            uint4 v = *(const uint4*)(X + ((size_t)s << 7) + l * 8);
            a0 += bf_lo(v.x); a1 += bf_hi(v.x);
            a2 += bf_lo(v.y); a3 += bf_hi(v.y);
            a4 += bf_lo(v.z); a5 += bf_hi(v.z);
            a6 += bf_lo(v.w); a7 += bf_hi(v.w);
        }
        float inv = 1.0f / (float)(dg > 1 ? dg : 1);
        uint4 p;
        p.x = (unsigned int)f2bf(a0 * inv) | ((unsigned int)f2bf(a1 * inv) << 16);
        p.y = (unsigned int)f2bf(a2 * inv) | ((unsigned int)f2bf(a3 * inv) << 16);
        p.z = (unsigned int)f2bf(a4 * inv) | ((unsigned int)f2bf(a5 * inv) << 16);
        p.w = (unsigned int)f2bf(a6 * inv) | ((unsigned int)f2bf(a7 * inv) << 16);
        *(uint4*)(mean + ((size_t)node << 7) + l * 8) = p;
    }
}

// ---------------- bf16 MFMA GEMM: 128 rows x 256 cols per block, 8 waves ----------------
// A = [A1 | A2] halves along K (ks<2 -> A1, else A2), row strides astr1/astr2.
// LDS rows: 8 x 16B granules, slot s of row r holds granule s ^ (r&7) (XOR swizzle
// on the global gather side; conflicts measured 0). Staged via global_load_lds.
// Wave grid 2x4: wave w -> rows (w>>2)*64.., cols (w&3)*64.. (4x4 MFMA tiles each).
__global__ __launch_bounds__(512) void gemm_mfma(
    const unsigned short* __restrict__ A1, const unsigned short* __restrict__ A2,
    int astr1, int astr2,
    const unsigned short* __restrict__ B,
    const float* __restrict__ biasBF, const float* __restrict__ biasF,
    unsigned short* __restrict__ outBF, float* __restrict__ outF,
    int N, int split, int reluBF) {
    __shared__ unsigned short As[128 * 64];   // 16 KB
    __shared__ unsigned short Bs[256 * 64];   // 32 KB (48 KB total -> 3 blocks/CU)
    int tid = threadIdx.x;
    int row0 = blockIdx.x * 128;
    int w = tid >> 6, lane = tid & 63;
    int wr = w >> 2, wc = w & 3;        // wave row-half / col-strip
    int q = lane >> 4, l16 = lane & 15;
    int rc = lane >> 3;                 // row within 8-row chunk
    int gsw = (lane & 7) ^ (rc & 7);    // swizzled granule to fetch

    f32x4 acc[4][4];
#pragma unroll
    for (int r = 0; r < 4; ++r)
#pragma unroll
        for (int c = 0; c < 4; ++c) acc[r][c] = (f32x4){0.f, 0.f, 0.f, 0.f};

    for (int ks = 0; ks < 4; ++ks) {
        int kbase = ks * 64;
        if (ks) __syncthreads();
        const unsigned short* Ap = (ks < 2) ? A1 : A2;
        int astr = (ks < 2) ? astr1 : astr2;
        int koff = (ks & 1) * 64;
        // A: 16 chunks of 8 rows; wave w stages chunks 2w, 2w+1
#pragma unroll
        for (int cc = 0; cc < 2; ++cc) {
            int c = w * 2 + cc;
            int grow = row0 + c * 8 + rc;
            if (grow > N - 1) grow = N - 1;   // clamp: garbage only pollutes unstored rows
            gl_lds16(Ap + (size_t)grow * astr + koff + gsw * 8, &As[c * 512]);
        }
        // B: 32 chunks of 8 rows; wave w stages chunks 4w..4w+3
#pragma unroll
        for (int cc = 0; cc < 4; ++cc) {
            int c = w * 4 + cc;
            int n = c * 8 + rc;
            gl_lds16(B + ((size_t)n << 8) + kbase + gsw * 8, &Bs[c * 512]);
        }
        __syncthreads();
#pragma unroll
        for (int k0 = 0; k0 < 64; k0 += 32) {
            int gb = (k0 >> 3) + q;
            int sl = gb ^ (l16 & 7);
            bf16x8 bfrag[4], afrag[4];
#pragma unroll
            for (int c = 0; c < 4; ++c) {
                int row = wc * 64 + c * 16 + l16;
                bfrag[c] = *(const bf16x8*)&Bs[row * 64 + sl * 8];
            }
#pragma unroll
            for (int r = 0; r < 4; ++r) {
                int row = wr * 64 + r * 16 + l16;
                afrag[r] = *(const bf16x8*)&As[row * 64 + sl * 8];
            }
#pragma unroll
            for (int r = 0; r < 4; ++r)
#pragma unroll
                for (int c = 0; c < 4; ++c)
                    acc[r][c] = __builtin_amdgcn_mfma_f32_16x16x32_bf16(afrag[r], bfrag[c], acc[r][c], 0, 0, 0);
        }
    }

    // epilogue: D col = lane&15, row = q*4 + reg
#pragma unroll
    for (int c = 0; c < 4; ++c) {
        int colg = wc * 64 + c * 16 + l16;
        bool isBF = (colg < split);
        float bb = 0.f;
        if (isBF) { if (biasBF) bb = biasBF[colg]; }
        else      bb = biasF[colg - split];
#pragma unroll
        for (int r = 0; r < 4; ++r) {
#pragma unroll
            for (int reg = 0; reg < 4; ++reg) {
                int rowg = row0 + wr * 64 + r * 16 + q * 4 + reg;
                if (rowg < N) {
                    float v = acc[r][c][reg] + bb;
                    if (isBF) {
                        if (reluBF) v = fmaxf(v, 0.f);
                        outBF[(size_t)rowg * split + colg] = f2bf(v);
                    } else {
                        outF[(size_t)rowg * (256 - split) + (colg - split)] = v;
                    }
                }
            }
        }
    }
}

// ---------------- agg2: out = mean_agg(P) + R (ushort nbr) ----------------
__global__ __launch_bounds__(256) void agg2_kernel(
    const unsigned short* __restrict__ P, const float* __restrict__ R,
    const int* __restrict__ row_start, const int* __restrict__ deg,
    const unsigned short* __restrict__ nbr, float* __restrict__ out) {
    int node = blockIdx.x * 16 + (threadIdx.x >> 4);
    int l = threadIdx.x & 15;
    if (node >= NN) return;
    int dg = deg[node];
    const unsigned short* sl = nbr + row_start[node];
    float a0 = 0.f, a1 = 0.f, a2 = 0.f, a3 = 0.f, a4 = 0.f, a5 = 0.f, a6 = 0.f, a7 = 0.f;
    int i = 0;
    for (; i + 8 <= dg; i += 8) {
        uint4 v[8];
#pragma unroll
        for (int u = 0; u < 8; ++u) {
            int s = sl[i + u];
            v[u] = *(const uint4*)(P + ((size_t)s << 7) + l * 8);
        }
#pragma unroll
        for (int u = 0; u < 8; ++u) {
            a0 += bf_lo(v[u].x); a1 += bf_hi(v[u].x);
            a2 += bf_lo(v[u].y); a3 += bf_hi(v[u].y);
            a4 += bf_lo(v[u].z); a5 += bf_hi(v[u].z);
            a6 += bf_lo(v[u].w); a7 += bf_hi(v[u].w);
        }
    }
    for (; i < dg; ++i) {
        int s = sl[i];
        uint4 v = *(const uint4*)(P + ((size_t)s << 7) + l * 8);
        a0 += bf_lo(v.x); a1 += bf_hi(v.x);
        a2 += bf_lo(v.y); a3 += bf_hi(v.y);
        a4 += bf_lo(v.z); a5 += bf_hi(v.z);
        a6 += bf_lo(v.w); a7 += bf_hi(v.w);
    }
    float inv = 1.0f / (float)(dg > 1 ? dg : 1);
    const float* rrow = R + ((size_t)node << 7) + l * 8;
    float4 r0 = *(const float4*)rrow;
    float4 r1 = *(const float4*)(rrow + 4);
    float4 o0, o1;
    o0.x = a0 * inv + r0.x; o0.y = a1 * inv + r0.y;
    o0.z = a2 * inv + r0.z; o0.w = a3 * inv + r0.w;
    o1.x = a4 * inv + r1.x; o1.y = a5 * inv + r1.y;
    o1.z = a6 * inv + r1.z; o1.w = a7 * inv + r1.w;
    float* orow = out + ((size_t)node << 7) + l * 8;
    *(float4*)orow = o0;
    *(float4*)(orow + 4) = o1;
}

extern "C" void kernel_launch(void* const* d_in, const int* in_sizes, int n_in,
                              void* d_out, int out_size, void* d_ws, size_t ws_size,
                              hipStream_t stream) {
    const float* x    = (const float*)d_in[0];
    const int*   edges = (const int*)d_in[1];
    const float* W1_l = (const float*)d_in[2];
    const float* b1   = (const float*)d_in[3];
    const float* W1_r = (const float*)d_in[4];
    const float* W2_l = (const float*)d_in[5];
    const float* b2   = (const float*)d_in[6];
    const float* W2_r = (const float*)d_in[7];
    float* out = (float*)d_out;

    const int N = NN;
    auto al = [](size_t v) { return (v + 255) & ~(size_t)255; };
    char* ws = (char*)d_ws;
    size_t o = 0;
    int* bcur = (int*)(ws + o); o += al((size_t)NBK * 4);
    unsigned int* packed = (unsigned int*)(ws + o); o += al((size_t)NBK * BUCKCAP * 4);
    unsigned short* nbr = (unsigned short*)(ws + o); o += al((size_t)NBK * BUCKCAP * 2);
    int* row_start = (int*)(ws + o); o += al((size_t)N * 4);
    int* deg       = (int*)(ws + o); o += al((size_t)N * 4);
    unsigned short* x_bf  = (unsigned short*)(ws + o); o += al((size_t)N * 128 * 2);
    unsigned short* mean1 = (unsigned short*)(ws + o); o += al((size_t)N * 128 * 2);
    unsigned short* h_bf  = (unsigned short*)(ws + o); o += al((size_t)N * 256 * 2);
    unsigned short* P_bf  = (unsigned short*)(ws + o); o += al((size_t)N * 128 * 2);
    float*          R_f   = (float*)(ws + o);          o += al((size_t)N * 128 * 4);
    unsigned short* B1    = (unsigned short*)(ws + o); o += al((size_t)256 * 256 * 2);
    unsigned short* B2    = (unsigned short*)(ws + o); o += al((size_t)256 * 256 * 2);

    // 1) zero bucket cursors + pack B1/B2
    prep_kernel<<<513, 256, 0, stream>>>(bcur, W1_l, W1_r, W2_l, W2_r, B1, B2);
    // 2) bin-scatter + cast_x in one dispatch
    mega_kernel<<<FILL_NB + CAST_NB, 256, 0, stream>>>(edges, bcur, packed, x, x_bf);
    // 3) per-bucket counting sort + mean1 aggregation (lists in LDS), CSR out for agg2
    pass2agg1_kernel<<<NBK, 512, 0, stream>>>(packed, bcur, x_bf, nbr, row_start, deg, mean1);
    // 4) h = relu([mean1||x_bf] @ B1^T + b1)  (bf16)
    gemm_mfma<<<(N + 127) / 128, 512, 0, stream>>>(mean1, x_bf, 128, 128, B1, b1, b1,
                                                   h_bf, (float*)nullptr, N, 256, 1);
    // 5) [P||R] = h @ B2^T ; P bf16 (no bias), R f32 (+b2)
    gemm_mfma<<<(N + 127) / 128, 512, 0, stream>>>(h_bf, h_bf + 128, 256, 256, B2,
                                                   (float*)nullptr, b2, P_bf, R_f, N, 128, 0);
    // 6) out = mean_agg(P) + R
    agg2_kernel<<<(N + 15) / 16, 256, 0, stream>>>(P_bf, R_f, row_start, deg, nbr, out);
}